// Round 5
// baseline (9979.937 us; speedup 1.0000x reference)
//
#include <hip/hip_runtime.h>
#include <cstdint>
#include <cstddef>

using u16 = unsigned short;
using u32 = unsigned int;

typedef __attribute__((ext_vector_type(8)))  __bf16 bf16x8;
typedef __attribute__((ext_vector_type(16))) float  f32x16;

constexpr int kB   = 512;
constexpr int kT   = 180;
constexpr int kH   = 768;
constexpr int NBLK = 96;    // 3 layers * 8 ntiles * 4 m-tiles
constexpr int NTHR = 512;   // 8 waves

constexpr int L0N  = 8 * 384 * 832;     // layer0 packed weight elems (26 chunks of 32)
constexpr int L12N = 8 * 384 * 1536;    // layer1/2 (48 chunks)

// h-ring: chunked layout [2 slots][24 kchunks][512 rows][32 k] bf16
constexpr int RING_SLOT_E = 24 * 512 * 32;               // 393,216 elems per slot
constexpr size_t RING_SZ  = (size_t)2 * RING_SLOT_E * 2; // 1,572,864 B

// workspace layout (bytes). Flags: 12 x 256B lines at ws+0 (zeroed).
constexpr size_t OFF_R0  = 4096;
constexpr size_t OFF_R1  = OFF_R0 + RING_SZ;
constexpr size_t OFF_R2  = OFF_R1 + RING_SZ;
constexpr size_t OFF_PB  = OFF_R2 + RING_SZ;             // zeroed region end
constexpr size_t OFF_XT  = OFF_PB + (size_t)3 * 3072 * 4;
constexpr size_t OFF_W0  = OFF_XT + (size_t)kT * kB * 64 * 2;
constexpr size_t OFF_W1  = OFF_W0 + (size_t)L0N * 2;
constexpr size_t OFF_W2  = OFF_W1 + (size_t)L12N * 2;
constexpr size_t WS_NEED = OFF_W2 + (size_t)L12N * 2;    // ~40.5 MB

// K-loop staging: 4 rotating 32KB dynamic-LDS stages (A 8KB + B 24KB each),
// prefetch distance 3 (1-stage reuse margin), steady vmcnt(8).
constexpr size_t STAGE_SZ = 32768;
constexpr int    NSTG     = 4;
constexpr size_t DYN_LDS  = NSTG * STAGE_SZ;             // 131,072 B

#define CLB __asm__ volatile("" ::: "memory")

__device__ __forceinline__ float bf2f(u16 u) {
  union { u32 i; float f; } v; v.i = ((u32)u) << 16; return v.f;
}
__device__ __forceinline__ u16 f2bf(float f) {
  union { float f; u32 i; } v; v.f = f;
  u32 r = v.i + 0x7fffu + ((v.i >> 16) & 1u);
  return (u16)(r >> 16);
}

// async global->LDS, 16B per lane (wave-uniform LDS base + lane*16; dests lane-linear)
typedef __attribute__((address_space(1))) const u32 as1_u32;
typedef __attribute__((address_space(3))) u32 as3_u32;
__device__ __forceinline__ void gload_lds16(const u16* g, u16* l) {
  __builtin_amdgcn_global_load_lds((as1_u32*)g, (as3_u32*)l, 16, 0, 0);
}
// SC1 (aux=16): agent-scope read, bypasses XCD-local L1/L2 — used ONLY for h-ring
// reads (cross-XCD producer->consumer). Proven correct rounds 2-4. The aggregate
// SC1 rate (~1.3 TB/s observed) is the current bottleneck; this round halves its
// volume (16 -> 8 ntile duplication) via the 96x512 block geometry.
__device__ __forceinline__ void gload_lds16_dc(const u16* g, u16* l) {
  __builtin_amdgcn_global_load_lds((as1_u32*)g, (as3_u32*)l, 16, 0, 16);
}

// ---------------------------------------------------------------- zero
__global__ void k_zero(uint4* p, int n) {
  uint4 z = make_uint4(0u, 0u, 0u, 0u);
  for (int i = blockIdx.x * 256 + threadIdx.x; i < n; i += gridDim.x * 256) p[i] = z;
}

// ---------------------------------------------------------------- weight pack
// [ntile(8)][pcol(384)][K] bf16, K-contiguous per column.
// pcol = gate*96 + hc (i,f,g,o); global gate col = gate*768 + ntile*96 + hc.
// L0 K=832: k<40 w_ih0 | 40..63 zero | 64..831 w_hh0. L1/2 K=1536: k<768 w_ih else w_hh.
__global__ void k_pack_w(const float* __restrict__ wih0, const float* __restrict__ whh0,
                         const float* __restrict__ wih1, const float* __restrict__ whh1,
                         const float* __restrict__ wih2, const float* __restrict__ whh2,
                         u16* __restrict__ W0, u16* __restrict__ W1, u16* __restrict__ W2) {
  int idx = blockIdx.x * 256 + threadIdx.x;
  if (idx < L0N) {
    int col = idx / 832, k = idx - col * 832;
    int ntile = col / 384, p = col - ntile * 384;
    int g = p / 96, hc = p - g * 96;
    int gcol = g * 768 + ntile * 96 + hc;
    float v = (k < 40) ? wih0[gcol * 40 + k]
                       : ((k < 64) ? 0.f : whh0[(size_t)gcol * 768 + (k - 64)]);
    W0[idx] = f2bf(v);
  } else if (idx < L0N + L12N) {
    int li = idx - L0N;
    int col = li / 1536, k = li - col * 1536;
    int ntile = col / 384, p = col - ntile * 384;
    int g = p / 96, hc = p - g * 96;
    int gcol = g * 768 + ntile * 96 + hc;
    float v = (k < 768) ? wih1[(size_t)gcol * 768 + k] : whh1[(size_t)gcol * 768 + (k - 768)];
    W1[li] = f2bf(v);
  } else {
    int li = idx - (L0N + L12N);
    if (li < L12N) {
      int col = li / 1536, k = li - col * 1536;
      int ntile = col / 384, p = col - ntile * 384;
      int g = p / 96, hc = p - g * 96;
      int gcol = g * 768 + ntile * 96 + hc;
      float v = (k < 768) ? wih2[(size_t)gcol * 768 + k] : whh2[(size_t)gcol * 768 + (k - 768)];
      W2[li] = f2bf(v);
    }
  }
}

// ---------------------------------------------------------------- bias pack
__global__ void k_pack_b(const float* __restrict__ bi0, const float* __restrict__ bh0,
                         const float* __restrict__ bi1, const float* __restrict__ bh1,
                         const float* __restrict__ bi2, const float* __restrict__ bh2,
                         float* __restrict__ pbo) {
  int idx = blockIdx.x * 256 + threadIdx.x;   // 3*3072
  int l = idx / 3072, r = idx - l * 3072;
  int ntile = r / 384, p = r - ntile * 384;
  int g = p / 96, hc = p - g * 96;
  int gcol = g * 768 + ntile * 96 + hc;
  const float* bi = (l == 0) ? bi0 : ((l == 1) ? bi1 : bi2);
  const float* bh = (l == 0) ? bh0 : ((l == 1) ? bh1 : bh2);
  pbo[idx] = bi[gcol] + bh[gcol];
}

// ---------------------------------------------------------------- x transform
// [B,T,40] f32 -> chunked [T][2 kchunks][512][32] bf16 (64-pad)
__global__ void k_xT(const float* __restrict__ x, u16* __restrict__ xT) {
  int idx = blockIdx.x * 256 + threadIdx.x;    // 180*512*64
  int t = idx / (512 * 64);
  int r = idx - t * 512 * 64;
  int b = r >> 6, j = r & 63;
  float v = (j < 40) ? x[((size_t)b * 180 + t) * 40 + j] : 0.f;
  xT[(size_t)t * 32768 + (size_t)(j >> 5) * 16384 + b * 32 + (j & 31)] = f2bf(v);
}

// ---------------------------------------------------------------- persistent dataflow LSTM
// 96 blocks x 512 threads (8 waves). Block (layer, ntile0..7, mt0..3): output tile
// 128 rows x 384 gate-cols. XCD = bid&7 = ntile -> weights (3 slices ~3MB) L2-resident.
// Dataflow flags F[layer][mt] (12 x 256B lines), 8 producers each:
//   input ready (l>=1):  F[l-1][mt] >= 8*(t+1)
//   recurrence  (t>=1):  F[l][mt]   >= 8*t
//   WAR backpressure (l<=1, t>=2): F[l+1][mt] >= 8*(t-1)
// Sum-semantics safe: per-block count <= t inductively, so sum>=8t => all ==t.
//
// K-loop: homogeneous glds/vmcnt skeleton (proven). Per chunk: 1 A-glds + 3 B-glds
// per thread into a 32KB stage (A[128][32k] 8KB @0, B[384][32k] 24KB @+8KB; pitch
// 64B, slot sp holds k-octet sp^((row>>1)&3) -> lane-linear dests, <=2-way banks).
// 4 stages, prefetch c+3, steady vmcnt(8), tail 4/0. Epilogue scratch [128][384]
// bf16 (96KB) aliases stages. Bias in registers (gate == wn -> wave-uniform).
__global__ __launch_bounds__(512, 2) void k_lstm(
    const u16* __restrict__ xT,
    u16* __restrict__ ring0, u16* __restrict__ ring1, u16* __restrict__ ring2,
    const u16* __restrict__ W0, const u16* __restrict__ W1, const u16* __restrict__ W2,
    const float* __restrict__ pb, u32* __restrict__ flg) {
  extern __shared__ __align__(16) unsigned char smem[];
  u16* scr = (u16*)smem;                 // epilogue scratch [128][384] (aliases stages)

  const int tid = threadIdx.x;
  const int bid = blockIdx.x;
  const int ntile = bid & 7;             // XCD = ntile -> weight slice L2-resident
  const int j0    = bid >> 3;            // 0..11
  const int layer = j0 >> 2;
  const int mt    = j0 & 3;
  const int mrow0 = mt * 128;

  const u16* Wl     = (layer == 0) ? W0 : ((layer == 1) ? W1 : W2);
  const int  Kl     = (layer == 0) ? 832 : 1536;
  const int  KcIn   = (layer == 0) ? 2 : 24;           // input k-chunks
  const int  nch    = (layer == 0) ? 26 : 48;
  const u16* inseq  = (layer == 1) ? ring0 : ring1;    // used by layers 1,2
  u16*       ringS  = (layer == 0) ? ring0 : ((layer == 1) ? ring1 : ring2);
  const u16* bbase0 = Wl + (size_t)(ntile * 384) * Kl;

  u32* Fself = flg + (size_t)((layer * 4 + mt) * 64);
  u32* Fin   = flg + (size_t)(((layer - 1) * 4 + mt) * 64);  // valid if layer>=1
  u32* Fnxt  = flg + (size_t)(((layer + 1) * 4 + mt) * 64);  // valid if layer<=1

  const int wid = tid >> 6, lane = tid & 63;
  const int wm = wid & 1, wn = wid >> 1;   // 2 m-halves x 4 n-quarters (= gate)
  const int l31 = lane & 31, lhi = lane >> 5;

  // bias in registers; gate index == wn (pcol = wn*96 + ni*32 + l31, ni*32+l31 < 96)
  float bias_r[3];
#pragma unroll
  for (int ni = 0; ni < 3; ni++)
    bias_r[ni] = pb[layer * 3072 + ntile * 384 + wn * 96 + ni * 32 + l31];

  float c_reg[24];
#pragma unroll
  for (int i = 0; i < 24; i++) c_reg[i] = 0.f;

  for (int t = 0; t < kT; ++t) {
    if (tid == 0) {
      auto spinf = [&](u32* f, u32 goal) {
        u32 tries = 0;
        while (__hip_atomic_load(f, __ATOMIC_RELAXED, __HIP_MEMORY_SCOPE_AGENT) < goal) {
          __builtin_amdgcn_s_sleep(4);
          if (++tries > 400000u) break;
        }
      };
      if (layer >= 1)           spinf(Fin,   8u * (u32)(t + 1));
      if (t >= 1)               spinf(Fself, 8u * (u32)t);
      if (layer <= 1 && t >= 2) spinf(Fnxt,  8u * (u32)(t - 1));
    }
    __syncthreads();

    f32x16 acc[2][3];
#pragma unroll
    for (int mi = 0; mi < 2; mi++)
#pragma unroll
      for (int ni = 0; ni < 3; ni++)
#pragma unroll
        for (int r = 0; r < 16; r++) acc[mi][ni][r] = 0.f;

    const u16* inbase  = (layer == 0) ? (xT + (size_t)t * 32768)
                                      : (inseq + (size_t)(t & 1) * RING_SLOT_E);
    const u16* recbase = ringS + (size_t)((t - 1) & 1) * RING_SLOT_E; // t=0 -> slot1 zeros

    // stage chunk c into stage st: A 1 glds/thread + B 3 glds/thread
    auto stage = [&](int c, int st) {
      u16* sbA = (u16*)(smem + (size_t)st * STAGE_SZ);
      u16* sbB = sbA + 4096;               // +8192 bytes
      const bool rsrc = (layer != 0) || (c >= KcIn);     // ring-sourced A chunk?
      const u16* abase = (c < KcIn) ? (inbase + (size_t)c * 16384)
                                    : (recbase + (size_t)(c - KcIn) * 16384);
      {
        const int e = tid;                 // 0..511 = 128 rows x 4 slots
        const int row = e >> 2, sp = e & 3;
        const int so = sp ^ ((row >> 1) & 3);
        const u16* ga = abase + (size_t)(mrow0 + row) * 32 + so * 8;
        u16*       la = sbA + (size_t)e * 8;
        if (rsrc) gload_lds16_dc(ga, la);
        else      gload_lds16(ga, la);
      }
      const u16* bb = bbase0 + c * 32;
#pragma unroll
      for (int k = 0; k < 3; k++) {
        const int e = tid + k * 512;       // 0..1535 = 384 cols x 4 slots
        const int col = e >> 2, sp = e & 3;
        const int so = sp ^ ((col >> 1) & 3);
        gload_lds16(bb + (size_t)col * Kl + so * 8, sbB + (size_t)e * 8);
      }
    };

    stage(0, 0);
    stage(1, 1);
    stage(2, 2);
    for (int c = 0; c < nch; ++c) {
      CLB;
      const int rem = nch - 1 - c;
      if      (rem >= 2) __builtin_amdgcn_s_waitcnt(0x0F78);  // vmcnt(8)
      else if (rem == 1) __builtin_amdgcn_s_waitcnt(0x0F74);  // vmcnt(4)
      else               __builtin_amdgcn_s_waitcnt(0x0F70);  // vmcnt(0)
      __builtin_amdgcn_s_barrier();
      CLB;
      if (c + 3 < nch) stage(c + 3, (c + 3) & 3);
      const u16* sA = (const u16*)(smem + (size_t)(c & 3) * STAGE_SZ);
      const u16* sB = sA + 4096;
      const int wsw = (l31 >> 1) & 3;
#pragma unroll
      for (int kk = 0; kk < 2; kk++) {
        const int sl = (((kk << 1) | lhi) ^ wsw) << 3;   // swizzled 16B slot
        bf16x8 a0 = *(const bf16x8*)(sA + (wm * 64 +      l31) * 32 + sl);
        bf16x8 a1 = *(const bf16x8*)(sA + (wm * 64 + 32 + l31) * 32 + sl);
        const int c0 = wn * 96 + l31;
        bf16x8 b0 = *(const bf16x8*)(sB + (c0     ) * 32 + sl);
        bf16x8 b1 = *(const bf16x8*)(sB + (c0 + 32) * 32 + sl);
        bf16x8 b2 = *(const bf16x8*)(sB + (c0 + 64) * 32 + sl);
        acc[0][0] = __builtin_amdgcn_mfma_f32_32x32x16_bf16(a0, b0, acc[0][0], 0, 0, 0);
        acc[0][1] = __builtin_amdgcn_mfma_f32_32x32x16_bf16(a0, b1, acc[0][1], 0, 0, 0);
        acc[0][2] = __builtin_amdgcn_mfma_f32_32x32x16_bf16(a0, b2, acc[0][2], 0, 0, 0);
        acc[1][0] = __builtin_amdgcn_mfma_f32_32x32x16_bf16(a1, b0, acc[1][0], 0, 0, 0);
        acc[1][1] = __builtin_amdgcn_mfma_f32_32x32x16_bf16(a1, b1, acc[1][1], 0, 0, 0);
        acc[1][2] = __builtin_amdgcn_mfma_f32_32x32x16_bf16(a1, b2, acc[1][2], 0, 0, 0);
      }
    }
    __syncthreads();   // all glds/ds_reads retired; protect stages before scr alias
    // epilogue: bias + nonlinearity (C/D: col=lane&31, row=(r&3)+8*(r>>2)+4*lhi)
#pragma unroll
    for (int mi = 0; mi < 2; mi++) {
#pragma unroll
      for (int ni = 0; ni < 3; ni++) {
        const int pcol = wn * 96 + ni * 32 + l31;
        const float bias = bias_r[ni];
#pragma unroll
        for (int r = 0; r < 16; r++) {
          const int rowl = wm * 64 + mi * 32 + (r & 3) + ((r >> 2) << 3) + (lhi << 2);
          float v = acc[mi][ni][r] + bias;
          v = (wn == 2) ? tanhf(v) : (1.f / (1.f + __expf(-v)));   // gate == wn
          scr[rowl * 384 + pcol] = f2bf(v);
        }
      }
    }
    __syncthreads();
    // pointwise cell update; c in registers; h to chunked ring slot t&1
    u16* hout = ringS + (size_t)(t & 1) * RING_SLOT_E;
#pragma unroll
    for (int jj = 0; jj < 24; jj++) {
      const int idx = jj * 512 + tid;        // 12288 = 128 rows x 96 h-cols
      const int row = idx / 96;
      const int hc  = idx - row * 96;
      const float iv = bf2f(scr[row * 384       + hc]);
      const float fv = bf2f(scr[row * 384 +  96 + hc]);
      const float gv = bf2f(scr[row * 384 + 192 + hc]);
      const float ov = bf2f(scr[row * 384 + 288 + hc]);
      const float cn = fv * c_reg[jj] + iv * gv;
      c_reg[jj] = cn;
      const int colg = ntile * 96 + hc;
      hout[(size_t)(colg >> 5) * 16384 + (size_t)(mrow0 + row) * 32 + (colg & 31)]
          = f2bf(ov * tanhf(cn));
    }
    __syncthreads();  // drains h-stores (HIP emits vmcnt(0) before s_barrier)
    if (tid == 0)
      __hip_atomic_fetch_add(Fself, 1u, __ATOMIC_RELEASE, __HIP_MEMORY_SCOPE_AGENT);
  }
}

// ---------------------------------------------------------------- projection + L2 norm
__global__ __launch_bounds__(256) void k_proj(const u16* __restrict__ hlast,
                                              const float* __restrict__ pw,
                                              const float* __restrict__ pbv,
                                              float* __restrict__ out) {
  __shared__ float hs[8 * 768];
  __shared__ float wred[4 * 8];
  __shared__ float inv[8];
  const int tid = threadIdx.x;
  const int r0 = blockIdx.x * 8;
  for (int i = tid; i < 8 * 768; i += 256) {
    const int b = i / 768, col = i - b * 768;   // chunked ring read
    hs[i] = bf2f(hlast[(size_t)(col >> 5) * 16384 + (size_t)(r0 + b) * 32 + (col & 31)]);
  }
  __syncthreads();
  float acc[8];
#pragma unroll
  for (int r = 0; r < 8; r++) acc[r] = 0.f;
  const float* wrow = pw + (size_t)tid * 768;
  for (int k = 0; k < 768; k++) {
    float w = wrow[k];
#pragma unroll
    for (int r = 0; r < 8; r++) acc[r] += hs[r * 768 + k] * w;
  }
  const float bv = pbv[tid];
#pragma unroll
  for (int r = 0; r < 8; r++) acc[r] += bv;
  const int lane = tid & 63, w4 = tid >> 6;
#pragma unroll
  for (int r = 0; r < 8; r++) {
    float v = acc[r] * acc[r];
#pragma unroll
    for (int off = 32; off > 0; off >>= 1) v += __shfl_xor(v, off);
    if (lane == 0) wred[w4 * 8 + r] = v;
  }
  __syncthreads();
  if (tid < 8) {
    float sum = wred[tid] + wred[8 + tid] + wred[16 + tid] + wred[24 + tid];
    inv[tid] = 1.f / sqrtf(sum);
  }
  __syncthreads();
#pragma unroll
  for (int r = 0; r < 8; r++) out[(size_t)(r0 + r) * 256 + tid] = acc[r] * inv[r];
}

// ---------------------------------------------------------------- host
extern "C" void kernel_launch(void* const* d_in, const int* in_sizes, int n_in,
                              void* d_out, int out_size, void* d_ws, size_t ws_size,
                              hipStream_t stream) {
  const float* x    = (const float*)d_in[0];
  const float* wih0 = (const float*)d_in[1];
  const float* whh0 = (const float*)d_in[2];
  const float* bi0  = (const float*)d_in[3];
  const float* bh0  = (const float*)d_in[4];
  const float* wih1 = (const float*)d_in[5];
  const float* whh1 = (const float*)d_in[6];
  const float* bi1  = (const float*)d_in[7];
  const float* bh1  = (const float*)d_in[8];
  const float* wih2 = (const float*)d_in[9];
  const float* whh2 = (const float*)d_in[10];
  const float* bi2  = (const float*)d_in[11];
  const float* bh2  = (const float*)d_in[12];
  const float* pw   = (const float*)d_in[13];
  const float* pbv  = (const float*)d_in[14];

  if (ws_size < WS_NEED) return;   // clean wrong answer, no OOB

  // one-time: allow >64KB dynamic LDS (pattern proven working rounds 3-4)
  static bool attr_done = false;
  if (!attr_done) {
    (void)hipFuncSetAttribute((const void*)k_lstm,
                              hipFuncAttributeMaxDynamicSharedMemorySize,
                              (int)DYN_LDS);
    attr_done = true;
  }

  char* ws  = (char*)d_ws;
  u32*  flg = (u32*)(ws + 0);
  u16*  r0  = (u16*)(ws + OFF_R0);
  u16*  r1  = (u16*)(ws + OFF_R1);
  u16*  r2  = (u16*)(ws + OFF_R2);
  float* pb = (float*)(ws + OFF_PB);
  u16*  xT  = (u16*)(ws + OFF_XT);
  u16*  W0  = (u16*)(ws + OFF_W0);
  u16*  W1  = (u16*)(ws + OFF_W1);
  u16*  W2  = (u16*)(ws + OFF_W2);

  hipLaunchKernelGGL(k_zero, dim3(512), dim3(256), 0, stream,
                     (uint4*)ws, (int)(OFF_PB / 16));
  hipLaunchKernelGGL(k_pack_w, dim3((L0N + 2 * L12N + 255) / 256), dim3(256), 0, stream,
                     wih0, whh0, wih1, whh1, wih2, whh2, W0, W1, W2);
  hipLaunchKernelGGL(k_pack_b, dim3(36), dim3(256), 0, stream,
                     bi0, bh0, bi1, bh1, bi2, bh2, pb);
  hipLaunchKernelGGL(k_xT, dim3(kT * kB * 64 / 256), dim3(256), 0, stream, x, xT);

  {
    const u16* xTc = xT; const float* pbc = pb;
    const u16 *W0c = W0, *W1c = W1, *W2c = W2;
    u16 *r0m = r0, *r1m = r1, *r2m = r2; u32* flgm = flg;
    void* kargs[] = {(void*)&xTc, (void*)&r0m, (void*)&r1m, (void*)&r2m,
                     (void*)&W0c, (void*)&W1c, (void*)&W2c, (void*)&pbc, (void*)&flgm};
    hipLaunchCooperativeKernel((void*)k_lstm, dim3(NBLK), dim3(NTHR), kargs,
                               (unsigned int)DYN_LDS, stream);
  }

  hipLaunchKernelGGL(k_proj, dim3(64), dim3(256), 0, stream,
                     r2 + (size_t)((kT - 1) & 1) * RING_SLOT_E, pw, pbv, (float*)d_out);
}

// Round 7
// 9381.676 us; speedup vs baseline: 1.0638x; 1.0638x over previous
//
#include <hip/hip_runtime.h>
#include <cstdint>
#include <cstddef>

using u16 = unsigned short;
using u32 = unsigned int;

typedef __attribute__((ext_vector_type(8)))  __bf16 bf16x8;
typedef __attribute__((ext_vector_type(16))) float  f32x16;

constexpr int kB   = 512;
constexpr int kT   = 180;
constexpr int kH   = 768;
constexpr int NBLK_RS = 256;  // rowsplit: 8 xcd * 2 rowslice * 16 ntile (1 block/CU)
constexpr int NBLK_FB = 192;  // fallback: 3 layers * 4 mtiles * 16 ntiles (R2 proven)

constexpr int L0N  = 16 * 192 * 832;    // packed weights, [ntile16][pcol192][K]
constexpr int L12N = 16 * 192 * 1536;

// h-ring: chunked layout [2 slots][24 kchunks][512 rows][32 k] bf16
constexpr int RING_SLOT_E = 24 * 512 * 32;               // 393,216 elems per slot
constexpr size_t RING_SZ  = (size_t)2 * RING_SLOT_E * 2; // 1,572,864 B

// workspace (bytes). ws+0..16384 zeroed sync area:
//   rowsplit flags F[xcd][rs][layer]: 48 x 256B lines   (bytes 0..12288)
//   xcd slot counters: 8 u32 at u32-index 3072          (bytes 12288..12320)
//   fallback grid-barrier counter at u32-index 3200     (byte 12800)
constexpr size_t OFF_R0  = 16384;
constexpr size_t OFF_R1  = OFF_R0 + RING_SZ;
constexpr size_t OFF_R2  = OFF_R1 + RING_SZ;
constexpr size_t OFF_PB  = OFF_R2 + RING_SZ;             // zeroed region end
constexpr size_t OFF_XT  = OFF_PB + (size_t)3 * 3072 * 4;
constexpr size_t OFF_W0  = OFF_XT + (size_t)kT * kB * 64 * 2;
constexpr size_t OFF_W1  = OFF_W0 + (size_t)L0N * 2;
constexpr size_t OFF_W2  = OFF_W1 + (size_t)L12N * 2;
constexpr size_t WS_NEED = OFF_W2 + (size_t)L12N * 2;    // ~40.5 MB

// rowsplit staging: 6 rotating 14KB stages (A 2KB @0 + B 12KB @+2KB), depth 5,
// 4 glds/WAVE/chunk -> 20 outstanding; steady vmcnt(16), tail 12/8/4/0.
constexpr size_t STAGE_SZ = 14336;
constexpr int    NSTG     = 6;
constexpr size_t DYN_LDS  = NSTG * STAGE_SZ;             // 86,016 B

#define CLB __asm__ volatile("" ::: "memory")

__device__ __forceinline__ float bf2f(u16 u) {
  union { u32 i; float f; } v; v.i = ((u32)u) << 16; return v.f;
}
__device__ __forceinline__ u16 f2bf(float f) {
  union { float f; u32 i; } v; v.f = f;
  u32 r = v.i + 0x7fffu + ((v.i >> 16) & 1u);
  return (u16)(r >> 16);
}

// async global->LDS, 16B per lane (wave-uniform LDS base + lane*16; dests lane-linear)
typedef __attribute__((address_space(1))) const u32 as1_u32;
typedef __attribute__((address_space(3))) u32 as3_u32;
__device__ __forceinline__ void gload_lds16(const u16* g, u16* l) {
  __builtin_amdgcn_global_load_lds((as1_u32*)g, (as3_u32*)l, 16, 0, 0);
}
// aux=1 (SC0): L1-bypass load served by the XCD-local L2. Rowsplit ring reads:
// producer/consumer share the physical XCD (binding via HW XCC_ID), stores are
// write-through to L2, release-add orders them before the flag -> coherent.
__device__ __forceinline__ void gload_lds16_l2(const u16* g, u16* l) {
  __builtin_amdgcn_global_load_lds((as1_u32*)g, (as3_u32*)l, 16, 0, 1);
}
// aux=16 (SC1): device-coherence-point read (fallback kernel's cross-XCD rings).
__device__ __forceinline__ void gload_lds16_dc(const u16* g, u16* l) {
  __builtin_amdgcn_global_load_lds((as1_u32*)g, (as3_u32*)l, 16, 0, 16);
}

// ---------------------------------------------------------------- zero
__global__ void k_zero(uint4* p, int n) {
  uint4 z = make_uint4(0u, 0u, 0u, 0u);
  for (int i = blockIdx.x * 256 + threadIdx.x; i < n; i += gridDim.x * 256) p[i] = z;
}

// ---------------------------------------------------------------- weight pack
// [ntile(16)][pcol(192)][K] bf16, K-contiguous per column.
// pcol = gate*48 + hc (i,f,g,o); global gate col = gate*768 + ntile*48 + hc.
// L0 K=832: k<40 w_ih0 | 40..63 zero | 64..831 w_hh0. L1/2 K=1536: k<768 ih else hh.
__global__ void k_pack_w(const float* __restrict__ wih0, const float* __restrict__ whh0,
                         const float* __restrict__ wih1, const float* __restrict__ whh1,
                         const float* __restrict__ wih2, const float* __restrict__ whh2,
                         u16* __restrict__ W0, u16* __restrict__ W1, u16* __restrict__ W2) {
  int idx = blockIdx.x * 256 + threadIdx.x;
  if (idx < L0N) {
    int col = idx / 832, k = idx - col * 832;
    int ntile = col / 192, p = col - ntile * 192;
    int g = p / 48, hc = p - g * 48;
    int gcol = g * 768 + ntile * 48 + hc;
    float v = (k < 40) ? wih0[gcol * 40 + k]
                       : ((k < 64) ? 0.f : whh0[(size_t)gcol * 768 + (k - 64)]);
    W0[idx] = f2bf(v);
  } else if (idx < L0N + L12N) {
    int li = idx - L0N;
    int col = li / 1536, k = li - col * 1536;
    int ntile = col / 192, p = col - ntile * 192;
    int g = p / 48, hc = p - g * 48;
    int gcol = g * 768 + ntile * 48 + hc;
    float v = (k < 768) ? wih1[(size_t)gcol * 768 + k] : whh1[(size_t)gcol * 768 + (k - 768)];
    W1[li] = f2bf(v);
  } else {
    int li = idx - (L0N + L12N);
    if (li < L12N) {
      int col = li / 1536, k = li - col * 1536;
      int ntile = col / 192, p = col - ntile * 192;
      int g = p / 48, hc = p - g * 48;
      int gcol = g * 768 + ntile * 48 + hc;
      float v = (k < 768) ? wih2[(size_t)gcol * 768 + k] : whh2[(size_t)gcol * 768 + (k - 768)];
      W2[li] = f2bf(v);
    }
  }
}

// ---------------------------------------------------------------- bias pack
__global__ void k_pack_b(const float* __restrict__ bi0, const float* __restrict__ bh0,
                         const float* __restrict__ bi1, const float* __restrict__ bh1,
                         const float* __restrict__ bi2, const float* __restrict__ bh2,
                         float* __restrict__ pbo) {
  int idx = blockIdx.x * 256 + threadIdx.x;   // 3*3072
  int l = idx / 3072, r = idx - l * 3072;
  int ntile = r / 192, p = r - ntile * 192;
  int g = p / 48, hc = p - g * 48;
  int gcol = g * 768 + ntile * 48 + hc;
  const float* bi = (l == 0) ? bi0 : ((l == 1) ? bi1 : bi2);
  const float* bh = (l == 0) ? bh0 : ((l == 1) ? bh1 : bh2);
  pbo[idx] = bi[gcol] + bh[gcol];
}

// ---------------------------------------------------------------- x transform
__global__ void k_xT(const float* __restrict__ x, u16* __restrict__ xT) {
  int idx = blockIdx.x * 256 + threadIdx.x;    // 180*512*64
  int t = idx / (512 * 64);
  int r = idx - t * 512 * 64;
  int b = r >> 6, j = r & 63;
  float v = (j < 40) ? x[((size_t)b * 180 + t) * 40 + j] : 0.f;
  xT[(size_t)t * 32768 + (size_t)(j >> 5) * 16384 + b * 32 + (j & 31)] = f2bf(v);
}

// ---------------------------------------------------------------- rowsplit LSTM
// Block binds to its PHYSICAL XCD via s_getreg(HW_REG_XCC_ID) [measured m09] and
// grabs slot = atomicAdd(xcnt[xcc]) -> rs=slot>>4, nt=slot&15. 86KB LDS forces
// 1 block/CU, 256 blocks on 256 CUs -> exactly 32 blocks/XCD (pigeonhole), so
// every (xcc, rs, nt) is covered exactly once REGARDLESS of dispatch mapping.
// Block owns rows [xcc*64+rs*32, +32), gate-cols [nt*192, +192), all 3 layers.
// h never crosses an XCD -> ring reads are local-L2 (aux=1); no SC1 anywhere.
// Flags F[xcc][rs][layer] count completions (16 blocks each):
//   l0(t): F0>=16t (t>=1); F1>=16(t-1) (t>=2)          [rec + WAR ring0 slot]
//   l1(t): F0>=16(t+1); F1>=16t (t>=1); F2>=16(t-1) (t>=2)
//   l2(t): F1>=16(t+1); F2>=16t (t>=1)
// K-loop: proven glds/vmcnt skeleton. 4 glds/wave/chunk (1 A exec-masked lane<32
// + 3 B) -> depth-5 = 20 outstanding; steady vmcnt(16) [R6 bug: waited 20 = no-op
// -> read unlanded LDS -> NaN], tail 12/8/4/0. Waves: wn2=wid&1 (96-col halves),
// kkw=wid>>1 (16-k halves, partials reduced in LDS).
__global__ __launch_bounds__(256, 1) void k_lstm_rs(
    const u16* __restrict__ xT,
    u16* __restrict__ ring0, u16* __restrict__ ring1, u16* __restrict__ ring2,
    const u16* __restrict__ W0, const u16* __restrict__ W1, const u16* __restrict__ W2,
    const float* __restrict__ pb, u32* __restrict__ flg) {
  extern __shared__ __align__(16) unsigned char smem[];
  float* red  = (float*)smem;            // 24,576B kk-reduction (aliases stages)
  u16*   scr2 = (u16*)(smem + 24576);    // 12,288B gate scratch [32][192] (aliases)
  __shared__ u32 meta[2];                // [0]=xcc, [1]=slot

  const int tid = threadIdx.x;
  if (tid == 0) {
    u32 xcc;
    asm volatile("s_getreg_b32 %0, hwreg(HW_REG_XCC_ID)" : "=s"(xcc));
    xcc &= 7u;
    u32* xcnt = flg + 3072;              // 8 counters, zeroed
    u32 slot = __hip_atomic_fetch_add(&xcnt[xcc], 1u, __ATOMIC_RELAXED,
                                      __HIP_MEMORY_SCOPE_AGENT);
    meta[0] = xcc; meta[1] = slot & 31u;
  }
  __syncthreads();
  const int xcc = (int)meta[0];
  const int rs  = (int)(meta[1] >> 4);   // 0/1
  const int nt  = (int)(meta[1] & 15u);  // 0..15
  const int r0  = xcc * 64 + rs * 32;

  const int wid = tid >> 6, lane = tid & 63;
  const int wn2 = wid & 1, kkw = wid >> 1;
  const int l31 = lane & 31, lhi = lane >> 5;

  u32* F0 = flg + (size_t)(((xcc * 2 + rs) * 3 + 0) * 64);
  u32* F1 = F0 + 64;
  u32* F2 = F0 + 128;

  auto spinf = [&](u32* f, u32 goal) {
    u32 tries = 0;
    while (__hip_atomic_load(f, __ATOMIC_RELAXED, __HIP_MEMORY_SCOPE_AGENT) < goal) {
      __builtin_amdgcn_s_sleep(4);
      if (++tries > 400000u) break;
    }
  };

  // bias in registers: pcol = wn2*96 + j*32 + l31
  float bias_r[3][3];
#pragma unroll
  for (int l = 0; l < 3; l++)
#pragma unroll
    for (int j = 0; j < 3; j++)
      bias_r[l][j] = pb[l * 3072 + nt * 192 + wn2 * 96 + j * 32 + l31];

  float cst[3][6];
#pragma unroll
  for (int l = 0; l < 3; l++)
#pragma unroll
    for (int j = 0; j < 6; j++) cst[l][j] = 0.f;

  for (int t = 0; t < kT; ++t) {
#pragma unroll
    for (int l = 0; l < 3; ++l) {
      const u16* Wl   = (l == 0) ? W0 : ((l == 1) ? W1 : W2);
      const int  Kl   = (l == 0) ? 832 : 1536;
      const int  KcIn = (l == 0) ? 2 : 24;
      const int  nch  = (l == 0) ? 26 : 48;
      u16* ringL = (l == 0) ? ring0 : ((l == 1) ? ring1 : ring2);
      const u16* inb  = (l == 0) ? (xT + (size_t)t * 32768)
                                 : (((l == 1) ? ring0 : ring1) + (size_t)(t & 1) * RING_SLOT_E);
      const u16* recb = ringL + (size_t)((t - 1) & 1) * RING_SLOT_E;  // t=0 -> slot1 zeros
      const u16* bb0  = Wl + (size_t)(nt * 192) * Kl;
      u32* Fl = (l == 0) ? F0 : ((l == 1) ? F1 : F2);

      if (tid == 0) {
        if (l == 0) {
          if (t >= 1) spinf(F0, 16u * (u32)t);
          if (t >= 2) spinf(F1, 16u * (u32)(t - 1));
        } else if (l == 1) {
          spinf(F0, 16u * (u32)(t + 1));
          if (t >= 1) spinf(F1, 16u * (u32)t);
          if (t >= 2) spinf(F2, 16u * (u32)(t - 1));
        } else {
          spinf(F1, 16u * (u32)(t + 1));
          if (t >= 1) spinf(F2, 16u * (u32)t);
        }
      }
      __syncthreads();

      f32x16 acc[3];
#pragma unroll
      for (int j = 0; j < 3; j++)
#pragma unroll
        for (int r = 0; r < 16; r++) acc[j][r] = 0.f;

      // stage chunk c into stage st: A 1 masked glds/wave + B 3 glds/thread
      auto stage = [&](int c, int st) {
        u16* sbA = (u16*)(smem + (size_t)st * STAGE_SZ);
        u16* sbB = sbA + 1024;             // +2048 bytes
        const bool rsrc = (l != 0) || (c >= KcIn);
        const u16* abase = (c < KcIn) ? (inb + (size_t)c * 16384)
                                      : (recb + (size_t)(c - KcIn) * 16384);
        if (lane < 32) {
          const int e = (wid << 5) | lane; // 0..127 = 32 rows x 4 slots
          const int row = e >> 2, sp = e & 3;
          const int so = sp ^ ((row >> 1) & 3);
          const u16* ga = abase + (size_t)(r0 + row) * 32 + so * 8;
          u16*       la = sbA + (size_t)e * 8;
          if (rsrc) gload_lds16_l2(ga, la);
          else      gload_lds16(ga, la);
        }
        const u16* bb = bb0 + c * 32;
#pragma unroll
        for (int k = 0; k < 3; k++) {
          const int e = wid * 192 + (k << 6) + lane;   // wave-contig 192-block
          const int col = e >> 2, sp = e & 3;
          const int so = sp ^ ((col >> 1) & 3);
          gload_lds16(bb + (size_t)col * Kl + so * 8, sbB + (size_t)e * 8);
        }
      };

      stage(0, 0); stage(1, 1); stage(2, 2); stage(3, 3); stage(4, 4);
      for (int c = 0; c < nch; ++c) {
        CLB;
        // 4 glds/wave/chunk, in-order: chunk c retired <=> vmcnt <= 4*min(4, rem)
        const int rem = nch - 1 - c;
        switch (rem > 3 ? 4 : rem) {
          case 0:  __builtin_amdgcn_s_waitcnt(0x0F70); break;  // vmcnt(0)
          case 1:  __builtin_amdgcn_s_waitcnt(0x0F74); break;  // vmcnt(4)
          case 2:  __builtin_amdgcn_s_waitcnt(0x0F78); break;  // vmcnt(8)
          case 3:  __builtin_amdgcn_s_waitcnt(0x0F7C); break;  // vmcnt(12)
          default: __builtin_amdgcn_s_waitcnt(0x4F70); break;  // vmcnt(16)
        }
        __builtin_amdgcn_s_barrier();
        CLB;
        if (c + 5 < nch) stage(c + 5, (c + 5) % NSTG);
        const u16* sA = (const u16*)(smem + (size_t)(c % NSTG) * STAGE_SZ);
        const u16* sB = sA + 1024;
        const int wsw = (l31 >> 1) & 3;
        const int sl = (((kkw << 1) | lhi) ^ wsw) << 3;  // this wave's 16-k half
        bf16x8 a  = *(const bf16x8*)(sA + l31 * 32 + sl);
        const int c0 = wn2 * 96 + l31;
        bf16x8 b0 = *(const bf16x8*)(sB + (c0     ) * 32 + sl);
        bf16x8 b1 = *(const bf16x8*)(sB + (c0 + 32) * 32 + sl);
        bf16x8 b2 = *(const bf16x8*)(sB + (c0 + 64) * 32 + sl);
        acc[0] = __builtin_amdgcn_mfma_f32_32x32x16_bf16(a, b0, acc[0], 0, 0, 0);
        acc[1] = __builtin_amdgcn_mfma_f32_32x32x16_bf16(a, b1, acc[1], 0, 0, 0);
        acc[2] = __builtin_amdgcn_mfma_f32_32x32x16_bf16(a, b2, acc[2], 0, 0, 0);
      }
      __syncthreads();   // all retired; stages dead -> red/scr2 alias safe

      // kk-reduction: kkw=1 publishes partials, kkw=0 reduces + nonlinearity
      if (kkw == 1) {
#pragma unroll
        for (int j = 0; j < 3; j++)
#pragma unroll
          for (int r = 0; r < 16; r++)
            red[(size_t)((wn2 * 3 + j) * 16 + r) * 64 + lane] = acc[j][r];
      }
      __syncthreads();
      if (kkw == 0) {
#pragma unroll
        for (int j = 0; j < 3; j++) {
          const int pcol = wn2 * 96 + j * 32 + l31;
          const int gate = pcol / 48;
          const float bias = bias_r[l][j];
#pragma unroll
          for (int r = 0; r < 16; r++) {
            const int rowl = (r & 3) + ((r >> 2) << 3) + (lhi << 2);
            float v = acc[j][r] + red[(size_t)((wn2 * 3 + j) * 16 + r) * 64 + lane] + bias;
            v = (gate == 2) ? tanhf(v) : (1.f / (1.f + __expf(-v)));
            scr2[rowl * 192 + pcol] = f2bf(v);
          }
        }
      }
      __syncthreads();
      // pointwise: 1536 = 32 rows x 48 h-cols; c-state in registers
      u16* hout = ringL + (size_t)(t & 1) * RING_SLOT_E;
#pragma unroll
      for (int jj = 0; jj < 6; jj++) {
        const int idx = jj * 256 + tid;
        const int row = idx / 48;
        const int hc  = idx - row * 48;
        const float iv = bf2f(scr2[row * 192       + hc]);
        const float fv = bf2f(scr2[row * 192 +  48 + hc]);
        const float gv = bf2f(scr2[row * 192 +  96 + hc]);
        const float ov = bf2f(scr2[row * 192 + 144 + hc]);
        const float cn = fv * cst[l][jj] + iv * gv;
        cst[l][jj] = cn;
        const int colg = nt * 48 + hc;
        hout[(size_t)(colg >> 5) * 16384 + (size_t)(r0 + row) * 32 + (colg & 31)]
            = f2bf(ov * tanhf(cn));
      }
      __syncthreads();  // drains all waves' h-stores (vmcnt(0) before s_barrier)
      if (tid == 0)
        __hip_atomic_fetch_add(Fl, 1u, __ATOMIC_RELEASE, __HIP_MEMORY_SCOPE_AGENT);
    }
  }
}

// ---------------------------------------------------------------- fallback: R2-proven kernel
// 192 blocks x 256 thr, static LDS, 3 stages depth-2, SC1 ring reads, grid barrier.
// Verified PASS at 9.3ms in round 2. Launched only if the rowsplit coop launch fails.
__global__ __launch_bounds__(256, 2) void k_lstm_fb(
    const u16* __restrict__ xT,
    u16* __restrict__ ring0, u16* __restrict__ ring1, u16* __restrict__ ring2,
    const u16* __restrict__ W0, const u16* __restrict__ W1, const u16* __restrict__ W2,
    const float* __restrict__ pb, u32* __restrict__ bar) {
  __shared__ __align__(16) unsigned char smem[61440 + 768];
  u16*   scr = (u16*)smem;
  float* pbs = (float*)(smem + 61440);

  const int tid = threadIdx.x;
  const int bid = blockIdx.x;
  const int xcd = bid & 7, j0 = bid >> 3;
  const int g_    = (j0 >> 2) * 8 + xcd;
  const int mt    = j0 & 3;
  const int layer = g_ >> 4;
  const int ntile = g_ & 15;
  const int mrow0 = mt * 128;

  const u16* Wl     = (layer == 0) ? W0 : ((layer == 1) ? W1 : W2);
  const int  Kl     = (layer == 0) ? 832 : 1536;
  const int  KcIn   = (layer == 0) ? 2 : 24;
  const int  nch    = (layer == 0) ? 26 : 48;
  const u16* inseq  = (layer == 1) ? ring0 : ring1;
  u16*       ringS  = (layer == 0) ? ring0 : ((layer == 1) ? ring1 : ring2);
  const u16* bbase0 = Wl + (size_t)(ntile * 192) * Kl;

  for (int i = tid; i < 192; i += 256) pbs[i] = pb[layer * 3072 + ntile * 192 + i];

  const int wid = tid >> 6, lane = tid & 63;
  const int wm = wid & 1, wn = wid >> 1;
  const int l31 = lane & 31, lhi = lane >> 5;

  float c_reg[24];
#pragma unroll
  for (int i = 0; i < 24; i++) c_reg[i] = 0.f;

  for (int s = 0; s < kT + 2; ++s) {
    const int t = s - layer;
    if (t >= 0 && t < kT) {
      f32x16 acc[2][3];
#pragma unroll
      for (int mi = 0; mi < 2; mi++)
#pragma unroll
        for (int ni = 0; ni < 3; ni++)
#pragma unroll
          for (int r = 0; r < 16; r++) acc[mi][ni][r] = 0.f;

      const u16* inbase  = (layer == 0) ? (xT + (size_t)t * 32768)
                                        : (inseq + (size_t)(t & 1) * RING_SLOT_E);
      const u16* recbase = ringS + (size_t)((t - 1) & 1) * RING_SLOT_E;

      auto stage = [&](int c, int st) {
        u16* sbA = (u16*)(smem + st * 20480);
        u16* sbB = sbA + 4096;
        const bool rsrc = (layer != 0) || (c >= KcIn);
        const u16* abase = (c < KcIn) ? (inbase + (size_t)c * 16384)
                                      : (recbase + (size_t)(c - KcIn) * 16384);
#pragma unroll
        for (int k = 0; k < 2; k++) {
          const int e = tid + k * 256;
          const int row = e >> 2, sp = e & 3;
          const int so = sp ^ ((row >> 1) & 3);
          const u16* ga = abase + (size_t)(mrow0 + row) * 32 + so * 8;
          u16*       la = sbA + (size_t)e * 8;
          if (rsrc) gload_lds16_dc(ga, la);
          else      gload_lds16(ga, la);
        }
        const u16* bb = bbase0 + c * 32;
#pragma unroll
        for (int k = 0; k < 3; k++) {
          const int e = tid + k * 256;
          const int col = e >> 2, sp = e & 3;
          const int so = sp ^ ((col >> 1) & 3);
          gload_lds16(bb + (size_t)col * Kl + so * 8, sbB + (size_t)e * 8);
        }
      };

      stage(0, 0);
      stage(1, 1);
      for (int c = 0; c < nch; ++c) {
        CLB;
        if (c == nch - 1) __builtin_amdgcn_s_waitcnt(0xF70);  // vmcnt(0)
        else              __builtin_amdgcn_s_waitcnt(0xF75);  // vmcnt(5)
        __builtin_amdgcn_s_barrier();
        CLB;
        if (c + 2 < nch) stage(c + 2, (c + 2) % 3);
        const u16* sA = (const u16*)(smem + (c % 3) * 20480);
        const u16* sB = sA + 4096;
        const int wsw = (l31 >> 1) & 3;
#pragma unroll
        for (int kk = 0; kk < 2; kk++) {
          const int sl = (((kk << 1) | lhi) ^ wsw) << 3;
          bf16x8 a0 = *(const bf16x8*)(sA + (wm * 64 +      l31) * 32 + sl);
          bf16x8 a1 = *(const bf16x8*)(sA + (wm * 64 + 32 + l31) * 32 + sl);
          const int c0 = wn * 96 + l31;
          bf16x8 b0 = *(const bf16x8*)(sB + (c0     ) * 32 + sl);
          bf16x8 b1 = *(const bf16x8*)(sB + (c0 + 32) * 32 + sl);
          bf16x8 b2 = *(const bf16x8*)(sB + (c0 + 64) * 32 + sl);
          acc[0][0] = __builtin_amdgcn_mfma_f32_32x32x16_bf16(a0, b0, acc[0][0], 0, 0, 0);
          acc[0][1] = __builtin_amdgcn_mfma_f32_32x32x16_bf16(a0, b1, acc[0][1], 0, 0, 0);
          acc[0][2] = __builtin_amdgcn_mfma_f32_32x32x16_bf16(a0, b2, acc[0][2], 0, 0, 0);
          acc[1][0] = __builtin_amdgcn_mfma_f32_32x32x16_bf16(a1, b0, acc[1][0], 0, 0, 0);
          acc[1][1] = __builtin_amdgcn_mfma_f32_32x32x16_bf16(a1, b1, acc[1][1], 0, 0, 0);
          acc[1][2] = __builtin_amdgcn_mfma_f32_32x32x16_bf16(a1, b2, acc[1][2], 0, 0, 0);
        }
      }
      __syncthreads();
#pragma unroll
      for (int mi = 0; mi < 2; mi++) {
#pragma unroll
        for (int ni = 0; ni < 3; ni++) {
          const int pcol = wn * 96 + ni * 32 + l31;
          const int gg = pcol / 48;
          const float bias = pbs[pcol];
#pragma unroll
          for (int r = 0; r < 16; r++) {
            const int rowl = wm * 64 + mi * 32 + (r & 3) + ((r >> 2) << 3) + (lhi << 2);
            float v = acc[mi][ni][r] + bias;
            v = (gg == 2) ? tanhf(v) : (1.f / (1.f + __expf(-v)));
            scr[rowl * 192 + pcol] = f2bf(v);
          }
        }
      }
      __syncthreads();
      u16* hout = ringS + (size_t)(t & 1) * RING_SLOT_E;
#pragma unroll
      for (int jj = 0; jj < 24; jj++) {
        const int idx = jj * 256 + tid;
        const int row = idx / 48;
        const int hc  = idx - row * 48;
        const float iv = bf2f(scr[row * 192       + hc]);
        const float fv = bf2f(scr[row * 192 +  48 + hc]);
        const float gv = bf2f(scr[row * 192 +  96 + hc]);
        const float ov = bf2f(scr[row * 192 + 144 + hc]);
        const float cn = fv * c_reg[jj] + iv * gv;
        c_reg[jj] = cn;
        const int colg = ntile * 48 + hc;
        hout[(size_t)(colg >> 5) * 16384 + (size_t)(mrow0 + row) * 32 + (colg & 31)]
            = f2bf(ov * tanhf(cn));
      }
    }
    __syncthreads();
    if (tid == 0) {
      __hip_atomic_fetch_add(bar, 1u, __ATOMIC_RELEASE, __HIP_MEMORY_SCOPE_AGENT);
      const u32 goal = (u32)(s + 1) * (u32)NBLK_FB;
      u32 tries = 0;
      while (__hip_atomic_load(bar, __ATOMIC_RELAXED, __HIP_MEMORY_SCOPE_AGENT) < goal) {
        __builtin_amdgcn_s_sleep(8);
        if (++tries > 100000u) break;
      }
    }
    __syncthreads();
  }
}

// ---------------------------------------------------------------- projection + L2 norm
__global__ __launch_bounds__(256) void k_proj(const u16* __restrict__ hlast,
                                              const float* __restrict__ pw,
                                              const float* __restrict__ pbv,
                                              float* __restrict__ out) {
  __shared__ float hs[8 * 768];
  __shared__ float wred[4 * 8];
  __shared__ float inv[8];
  const int tid = threadIdx.x;
  const int r0 = blockIdx.x * 8;
  for (int i = tid; i < 8 * 768; i += 256) {
    const int b = i / 768, col = i - b * 768;
    hs[i] = bf2f(hlast[(size_t)(col >> 5) * 16384 + (size_t)(r0 + b) * 32 + (col & 31)]);
  }
  __syncthreads();
  float acc[8];
#pragma unroll
  for (int r = 0; r < 8; r++) acc[r] = 0.f;
  const float* wrow = pw + (size_t)tid * 768;
  for (int k = 0; k < 768; k++) {
    float w = wrow[k];
#pragma unroll
    for (int r = 0; r < 8; r++) acc[r] += hs[r * 768 + k] * w;
  }
  const float bv = pbv[tid];
#pragma unroll
  for (int r = 0; r < 8; r++) acc[r] += bv;
  const int lane = tid & 63, w4 = tid >> 6;
#pragma unroll
  for (int r = 0; r < 8; r++) {
    float v = acc[r] * acc[r];
#pragma unroll
    for (int off = 32; off > 0; off >>= 1) v += __shfl_xor(v, off);
    if (lane == 0) wred[w4 * 8 + r] = v;
  }
  __syncthreads();
  if (tid < 8) {
    float sum = wred[tid] + wred[8 + tid] + wred[16 + tid] + wred[24 + tid];
    inv[tid] = 1.f / sqrtf(sum);
  }
  __syncthreads();
#pragma unroll
  for (int r = 0; r < 8; r++) out[(size_t)(r0 + r) * 256 + tid] = acc[r] * inv[r];
}

// ---------------------------------------------------------------- host
extern "C" void kernel_launch(void* const* d_in, const int* in_sizes, int n_in,
                              void* d_out, int out_size, void* d_ws, size_t ws_size,
                              hipStream_t stream) {
  const float* x    = (const float*)d_in[0];
  const float* wih0 = (const float*)d_in[1];
  const float* whh0 = (const float*)d_in[2];
  const float* bi0  = (const float*)d_in[3];
  const float* bh0  = (const float*)d_in[4];
  const float* wih1 = (const float*)d_in[5];
  const float* whh1 = (const float*)d_in[6];
  const float* bi1  = (const float*)d_in[7];
  const float* bh1  = (const float*)d_in[8];
  const float* wih2 = (const float*)d_in[9];
  const float* whh2 = (const float*)d_in[10];
  const float* bi2  = (const float*)d_in[11];
  const float* bh2  = (const float*)d_in[12];
  const float* pw   = (const float*)d_in[13];
  const float* pbv  = (const float*)d_in[14];

  if (ws_size < WS_NEED) return;   // clean wrong answer, no OOB

  // one-time host-side feasibility queries (no stream ops; capture-safe)
  static int mode = -1;   // 1 = rowsplit, 0 = fallback
  if (mode < 0) {
    hipError_t e1 = hipFuncSetAttribute((const void*)k_lstm_rs,
                                        hipFuncAttributeMaxDynamicSharedMemorySize,
                                        (int)DYN_LDS);
    int nb = 0;
    hipError_t e2 = hipOccupancyMaxActiveBlocksPerMultiprocessor(
        &nb, k_lstm_rs, 256, (size_t)DYN_LDS);
    int dev = 0; hipGetDevice(&dev);
    hipDeviceProp_t props{};
    hipError_t e3 = hipGetDeviceProperties(&props, dev);
    mode = (e1 == hipSuccess && e2 == hipSuccess && e3 == hipSuccess &&
            nb >= 1 && props.multiProcessorCount >= NBLK_RS) ? 1 : 0;
  }

  char* ws  = (char*)d_ws;
  u32*  flg = (u32*)(ws + 0);
  u32*  bar = flg + 3200;                 // fallback grid-barrier counter (zeroed)
  u16*  r0  = (u16*)(ws + OFF_R0);
  u16*  r1  = (u16*)(ws + OFF_R1);
  u16*  r2  = (u16*)(ws + OFF_R2);
  float* pb = (float*)(ws + OFF_PB);
  u16*  xT  = (u16*)(ws + OFF_XT);
  u16*  W0  = (u16*)(ws + OFF_W0);
  u16*  W1  = (u16*)(ws + OFF_W1);
  u16*  W2  = (u16*)(ws + OFF_W2);

  hipLaunchKernelGGL(k_zero, dim3(512), dim3(256), 0, stream,
                     (uint4*)ws, (int)(OFF_PB / 16));
  hipLaunchKernelGGL(k_pack_w, dim3((L0N + 2 * L12N + 255) / 256), dim3(256), 0, stream,
                     wih0, whh0, wih1, whh1, wih2, whh2, W0, W1, W2);
  hipLaunchKernelGGL(k_pack_b, dim3(36), dim3(256), 0, stream,
                     bi0, bh0, bi1, bh1, bi2, bh2, pb);
  hipLaunchKernelGGL(k_xT, dim3(kT * kB * 64 / 256), dim3(256), 0, stream, x, xT);

  {
    const u16* xTc = xT; const float* pbc = pb;
    const u16 *W0c = W0, *W1c = W1, *W2c = W2;
    u16 *r0m = r0, *r1m = r1, *r2m = r2;
    u32* flgm = flg; u32* barm = bar;
    void* kargs_rs[] = {(void*)&xTc, (void*)&r0m, (void*)&r1m, (void*)&r2m,
                        (void*)&W0c, (void*)&W1c, (void*)&W2c, (void*)&pbc, (void*)&flgm};
    void* kargs_fb[] = {(void*)&xTc, (void*)&r0m, (void*)&r1m, (void*)&r2m,
                        (void*)&W0c, (void*)&W1c, (void*)&W2c, (void*)&pbc, (void*)&barm};
    if (mode == 1) {
      hipError_t le = hipLaunchCooperativeKernel((void*)k_lstm_rs, dim3(NBLK_RS),
                                                 dim3(256), kargs_rs,
                                                 (unsigned int)DYN_LDS, stream);
      if (le != hipSuccess) mode = 0;     // rejected synchronously -> fall back
    }
    if (mode == 0) {
      hipLaunchCooperativeKernel((void*)k_lstm_fb, dim3(NBLK_FB), dim3(256),
                                 kargs_fb, 0, stream);
    }
  }

  hipLaunchKernelGGL(k_proj, dim3(64), dim3(256), 0, stream,
                     r2 + (size_t)((kT - 1) & 1) * RING_SLOT_E, pw, pbv, (float*)d_out);
}

// Round 8
// 9037.479 us; speedup vs baseline: 1.1043x; 1.0381x over previous
//
#include <hip/hip_runtime.h>
#include <cstdint>
#include <cstddef>

using u16 = unsigned short;
using u32 = unsigned int;

typedef __attribute__((ext_vector_type(8)))  __bf16 bf16x8;
typedef __attribute__((ext_vector_type(16))) float  f32x16;

constexpr int kB   = 512;
constexpr int kT   = 180;
constexpr int kH   = 768;
constexpr int NBLK = 192;   // 3 layers * (4 m-tiles * 16 n-tiles)

constexpr int L0N  = 16 * 192 * 832;    // layer0 packed weight elems (26 chunks of 32)
constexpr int L12N = 16 * 192 * 1536;   // layer1/2 (48 chunks)

// h-ring: chunked layout [2 slots][24 kchunks][512 rows][32 k] bf16
constexpr int RING_SLOT_E = 24 * 512 * 32;               // 393,216 elems per slot
constexpr size_t RING_SZ  = (size_t)2 * RING_SLOT_E * 2; // 1,572,864 B

// workspace layout (bytes). Flags: 12 x 256B lines at ws+0 (zeroed).
constexpr size_t OFF_R0  = 4096;
constexpr size_t OFF_R1  = OFF_R0 + RING_SZ;
constexpr size_t OFF_R2  = OFF_R1 + RING_SZ;
constexpr size_t OFF_PB  = OFF_R2 + RING_SZ;             // zeroed region end
constexpr size_t OFF_XT  = OFF_PB + (size_t)3 * 3072 * 4;
constexpr size_t OFF_W0  = OFF_XT + (size_t)kT * kB * 64 * 2;
constexpr size_t OFF_W1  = OFF_W0 + (size_t)L0N * 2;
constexpr size_t OFF_W2  = OFF_W1 + (size_t)L12N * 2;
constexpr size_t WS_NEED = OFF_W2 + (size_t)L12N * 2;    // ~40.5 MB

// deep pipeline: 6 rotating 20KB dynamic-LDS stages, 5 chunks in flight
constexpr int    NSTAGE   = 6;
constexpr size_t STAGE_SZ = 20480;
constexpr size_t DYN_LDS  = NSTAGE * STAGE_SZ + 768;     // 123,648 B

#define CLB __asm__ volatile("" ::: "memory")

__device__ __forceinline__ float bf2f(u16 u) {
  union { u32 i; float f; } v; v.i = ((u32)u) << 16; return v.f;
}
__device__ __forceinline__ u16 f2bf(float f) {
  union { float f; u32 i; } v; v.f = f;
  u32 r = v.i + 0x7fffu + ((v.i >> 16) & 1u);
  return (u16)(r >> 16);
}

// async global->LDS, 16B per lane (wave-uniform LDS base + lane*16; dests lane-linear)
// Round 8: ALL reads cached (aux=0). Measured walls: SC1 uncached path saturates at
// ~1.35 TB/s (R2/R4, depth-insensitive); cached L3->L2 fabric does ~4.5 TB/s (R7
// rowsplit). Coherence for cross-XCD h now uses the R0-proven scheme: producer
// RELEASE-add (buffer_wbl2 publishes dirty h) + consumer __threadfence() acquire
// (buffer_inv) after the flag spin, before any ring read of the step. Cached reads
// additionally dedup in L2 (the 2 co-XCD ntile-twins of each (layer,mt) share fills).
typedef __attribute__((address_space(1))) const u32 as1_u32;
typedef __attribute__((address_space(3))) u32 as3_u32;
__device__ __forceinline__ void gload_lds16(const u16* g, u16* l) {
  __builtin_amdgcn_global_load_lds((as1_u32*)g, (as3_u32*)l, 16, 0, 0);
}

// ---------------------------------------------------------------- zero
__global__ void k_zero(uint4* p, int n) {
  uint4 z = make_uint4(0u, 0u, 0u, 0u);
  for (int i = blockIdx.x * 256 + threadIdx.x; i < n; i += gridDim.x * 256) p[i] = z;
}

// ---------------------------------------------------------------- weight pack
__global__ void k_pack_w(const float* __restrict__ wih0, const float* __restrict__ whh0,
                         const float* __restrict__ wih1, const float* __restrict__ whh1,
                         const float* __restrict__ wih2, const float* __restrict__ whh2,
                         u16* __restrict__ W0, u16* __restrict__ W1, u16* __restrict__ W2) {
  int idx = blockIdx.x * 256 + threadIdx.x;
  if (idx < L0N) {
    int col = idx / 832, k = idx - col * 832;
    int ntile = col / 192, p = col - ntile * 192;
    int g = p / 48, hc = p - g * 48;
    int gcol = g * 768 + ntile * 48 + hc;
    float v = (k < 40) ? wih0[gcol * 40 + k]
                       : ((k < 64) ? 0.f : whh0[(size_t)gcol * 768 + (k - 64)]);
    W0[idx] = f2bf(v);
  } else if (idx < L0N + L12N) {
    int li = idx - L0N;
    int col = li / 1536, k = li - col * 1536;
    int ntile = col / 192, p = col - ntile * 192;
    int g = p / 48, hc = p - g * 48;
    int gcol = g * 768 + ntile * 48 + hc;
    float v = (k < 768) ? wih1[(size_t)gcol * 768 + k] : whh1[(size_t)gcol * 768 + (k - 768)];
    W1[li] = f2bf(v);
  } else {
    int li = idx - (L0N + L12N);
    if (li < L12N) {
      int col = li / 1536, k = li - col * 1536;
      int ntile = col / 192, p = col - ntile * 192;
      int g = p / 48, hc = p - g * 48;
      int gcol = g * 768 + ntile * 48 + hc;
      float v = (k < 768) ? wih2[(size_t)gcol * 768 + k] : whh2[(size_t)gcol * 768 + (k - 768)];
      W2[li] = f2bf(v);
    }
  }
}

// ---------------------------------------------------------------- bias pack
__global__ void k_pack_b(const float* __restrict__ bi0, const float* __restrict__ bh0,
                         const float* __restrict__ bi1, const float* __restrict__ bh1,
                         const float* __restrict__ bi2, const float* __restrict__ bh2,
                         float* __restrict__ pbo) {
  int idx = blockIdx.x * 256 + threadIdx.x;   // 3*3072
  int l = idx / 3072, r = idx - l * 3072;
  int ntile = r / 192, p = r - ntile * 192;
  int g = p / 48, hc = p - g * 48;
  int gcol = g * 768 + ntile * 48 + hc;
  const float* bi = (l == 0) ? bi0 : ((l == 1) ? bi1 : bi2);
  const float* bh = (l == 0) ? bh0 : ((l == 1) ? bh1 : bh2);
  pbo[idx] = bi[gcol] + bh[gcol];
}

// ---------------------------------------------------------------- x transform
__global__ void k_xT(const float* __restrict__ x, u16* __restrict__ xT) {
  int idx = blockIdx.x * 256 + threadIdx.x;    // 180*512*64
  int t = idx / (512 * 64);
  int r = idx - t * 512 * 64;
  int b = r >> 6, j = r & 63;
  float v = (j < 40) ? x[((size_t)b * 180 + t) * 40 + j] : 0.f;
  xT[(size_t)t * 32768 + (size_t)(j >> 5) * 16384 + b * 32 + (j & 31)] = f2bf(v);
}

// ================================================================ LSTM kernel body
// DATAFLOW SYNC (proven R4): 12 counting flags F[layer][mt] (one 256B line each).
//   input ready (l>=1):  F[l-1][mt] >= 16*(t+1)
//   recurrence  (t>=1):  F[l][mt]   >= 16*t
//   WAR backpressure (l<=1, t>=2): F[l+1][mt] >= 16*(t-1)
// COHERENCE (proven R0): producer RELEASE-add publishes h (wbl2); consumer does
// __threadfence() (acquire -> buffer_inv) after its spins, before any ring read.
// All ring reads are CACHED (aux=0) -> served by the ~4.5 TB/s fabric with L2
// dedup, instead of the ~1.35 TB/s SC1 uncached wall (R2-R7 measurements).
// K-loop: proven glds/vmcnt skeleton. DEEP=1: 6 dynamic-LDS stages, 5 chunks in
// flight, 5 glds/thread/chunk -> steady vmcnt(20), tail 15/10/5/0. DEEP=0: static
// 3-stage depth-2 (vmcnt(5) steady).
#define LSTM_BODY(SMEM_DECL, SMEM_PTR, NSTG, DEEP)                                     \
  SMEM_DECL;                                                                           \
  u16*   scr = (u16*)(SMEM_PTR);                                                       \
  float* pbs = (float*)((SMEM_PTR) + (size_t)(NSTG) * STAGE_SZ);                       \
  const int tid = threadIdx.x;                                                         \
  const int bid = blockIdx.x;                                                          \
  const int xcd = bid & 7, j0 = bid >> 3;                                              \
  const int g_    = (j0 >> 2) * 8 + xcd;                                               \
  const int mt    = j0 & 3;                                                            \
  const int layer = g_ >> 4;                                                           \
  const int ntile = g_ & 15;                                                           \
  const int mrow0 = mt * 128;                                                          \
  const u16* Wl     = (layer == 0) ? W0 : ((layer == 1) ? W1 : W2);                    \
  const int  Kl     = (layer == 0) ? 832 : 1536;                                       \
  const int  KcIn   = (layer == 0) ? 2 : 24;                                           \
  const int  nch    = (layer == 0) ? 26 : 48;                                          \
  const u16* inseq  = (layer == 1) ? ring0 : ring1;                                    \
  u16*       ringS  = (layer == 0) ? ring0 : ((layer == 1) ? ring1 : ring2);           \
  const u16* bbase0 = Wl + (size_t)(ntile * 192) * Kl;                                 \
  u32* Fself = flg + (size_t)(((layer << 2) | mt) * 64);                               \
  u32* Fin   = flg + (size_t)((((layer - 1) << 2) | mt) * 64);  /* valid if l>=1 */    \
  u32* Fnxt  = flg + (size_t)((((layer + 1) << 2) | mt) * 64);  /* valid if l<=1 */    \
  for (int i = tid; i < 192; i += 256) pbs[i] = pb[layer * 3072 + ntile * 192 + i];    \
  const int wid = tid >> 6, lane = tid & 63;                                           \
  const int wm = wid & 1, wn = wid >> 1;                                               \
  const int l31 = lane & 31, lhi = lane >> 5;                                          \
  float c_reg[24];                                                                     \
  _Pragma("unroll")                                                                    \
  for (int i = 0; i < 24; i++) c_reg[i] = 0.f;                                         \
  for (int t = 0; t < kT; ++t) {                                                       \
    if (tid == 0) {                                                                    \
      auto spinf = [&](u32* f, u32 goal) {                                             \
        u32 tries = 0;                                                                 \
        while (__hip_atomic_load(f, __ATOMIC_RELAXED, __HIP_MEMORY_SCOPE_AGENT) < goal) {\
          __builtin_amdgcn_s_sleep(4);                                                 \
          if (++tries > 400000u) break;                                                \
        }                                                                              \
      };                                                                               \
      if (layer >= 1)           spinf(Fin,   16u * (u32)(t + 1));                      \
      if (t >= 1)               spinf(Fself, 16u * (u32)t);                            \
      if (layer <= 1 && t >= 2) spinf(Fnxt,  16u * (u32)(t - 1));                      \
      __threadfence();  /* acquire: buffer_inv -> fresh cross-XCD h (R0-proven) */     \
    }                                                                                  \
    __syncthreads();                                                                   \
    {                                                                                  \
      f32x16 acc[2][3];                                                                \
      _Pragma("unroll")                                                                \
      for (int mi = 0; mi < 2; mi++)                                                   \
        for (int ni = 0; ni < 3; ni++)                                                 \
          for (int r = 0; r < 16; r++) acc[mi][ni][r] = 0.f;                           \
      const u16* inbase  = (layer == 0) ? (xT + (size_t)t * 32768)                     \
                                        : (inseq + (size_t)(t & 1) * RING_SLOT_E);     \
      const u16* recbase = ringS + (size_t)((t - 1) & 1) * RING_SLOT_E;                \
      auto stage = [&](int c, int st) {                                                \
        u16* sbA = (u16*)((SMEM_PTR) + (size_t)st * STAGE_SZ);                         \
        u16* sbB = sbA + 4096;                                                         \
        const u16* abase = (c < KcIn) ? (inbase + (size_t)c * 16384)                   \
                                      : (recbase + (size_t)(c - KcIn) * 16384);        \
        _Pragma("unroll")                                                              \
        for (int k = 0; k < 2; k++) {                                                  \
          const int e = tid + k * 256;                                                 \
          const int row = e >> 2, sp = e & 3;                                          \
          const int so = sp ^ ((row >> 1) & 3);                                        \
          gload_lds16(abase + (size_t)(mrow0 + row) * 32 + so * 8, sbA + (size_t)e * 8);\
        }                                                                              \
        const u16* bb = bbase0 + c * 32;                                               \
        _Pragma("unroll")                                                              \
        for (int k = 0; k < 3; k++) {                                                  \
          const int e = tid + k * 256;                                                 \
          const int col = e >> 2, sp = e & 3;                                          \
          const int so = sp ^ ((col >> 1) & 3);                                        \
          gload_lds16(bb + (size_t)col * Kl + so * 8, sbB + (size_t)e * 8);            \
        }                                                                              \
      };                                                                               \
      if (DEEP) { stage(0,0); stage(1,1); stage(2,2); stage(3,3); stage(4,4); }        \
      else      { stage(0,0); stage(1,1); }                                            \
      for (int c = 0; c < nch; ++c) {                                                  \
        CLB;                                                                           \
        const int rem = nch - 1 - c;                                                   \
        if (DEEP) {                                                                    \
          switch (rem > 4 ? 4 : rem) {                                                 \
            case 0:  __builtin_amdgcn_s_waitcnt(0x0F70); break; /* vmcnt(0)  */        \
            case 1:  __builtin_amdgcn_s_waitcnt(0x0F75); break; /* vmcnt(5)  */        \
            case 2:  __builtin_amdgcn_s_waitcnt(0x0F7A); break; /* vmcnt(10) */        \
            case 3:  __builtin_amdgcn_s_waitcnt(0x0F7F); break; /* vmcnt(15) */        \
            default: __builtin_amdgcn_s_waitcnt(0x4F74); break; /* vmcnt(20) */        \
          }                                                                            \
        } else {                                                                       \
          if (rem == 0) __builtin_amdgcn_s_waitcnt(0x0F70);     /* vmcnt(0)  */        \
          else          __builtin_amdgcn_s_waitcnt(0x0F75);     /* vmcnt(5)  */        \
        }                                                                              \
        __builtin_amdgcn_s_barrier();                                                  \
        CLB;                                                                           \
        const int pf = DEEP ? 5 : 2;                                                   \
        if (c + pf < nch) stage(c + pf, (c + pf) % (NSTG));                            \
        const u16* sA = (const u16*)((SMEM_PTR) + (size_t)(c % (NSTG)) * STAGE_SZ);    \
        const u16* sB = sA + 4096;                                                     \
        const int wsw = (l31 >> 1) & 3;                                                \
        _Pragma("unroll")                                                              \
        for (int kk = 0; kk < 2; kk++) {                                               \
          const int sl = (((kk << 1) | lhi) ^ wsw) << 3;                               \
          bf16x8 a0 = *(const bf16x8*)(sA + (wm * 64 +      l31) * 32 + sl);           \
          bf16x8 a1 = *(const bf16x8*)(sA + (wm * 64 + 32 + l31) * 32 + sl);           \
          const int c0 = wn * 96 + l31;                                                \
          bf16x8 b0 = *(const bf16x8*)(sB + (c0     ) * 32 + sl);                      \
          bf16x8 b1 = *(const bf16x8*)(sB + (c0 + 32) * 32 + sl);                      \
          bf16x8 b2 = *(const bf16x8*)(sB + (c0 + 64) * 32 + sl);                      \
          acc[0][0] = __builtin_amdgcn_mfma_f32_32x32x16_bf16(a0, b0, acc[0][0],0,0,0);\
          acc[0][1] = __builtin_amdgcn_mfma_f32_32x32x16_bf16(a0, b1, acc[0][1],0,0,0);\
          acc[0][2] = __builtin_amdgcn_mfma_f32_32x32x16_bf16(a0, b2, acc[0][2],0,0,0);\
          acc[1][0] = __builtin_amdgcn_mfma_f32_32x32x16_bf16(a1, b0, acc[1][0],0,0,0);\
          acc[1][1] = __builtin_amdgcn_mfma_f32_32x32x16_bf16(a1, b1, acc[1][1],0,0,0);\
          acc[1][2] = __builtin_amdgcn_mfma_f32_32x32x16_bf16(a1, b2, acc[1][2],0,0,0);\
        }                                                                              \
      }                                                                                \
      __syncthreads();                                                                 \
      _Pragma("unroll")                                                                \
      for (int mi = 0; mi < 2; mi++) {                                                 \
        _Pragma("unroll")                                                              \
        for (int ni = 0; ni < 3; ni++) {                                               \
          const int pcol = wn * 96 + ni * 32 + l31;                                    \
          const int gg = pcol / 48;                                                    \
          const float bias = pbs[pcol];                                                \
          _Pragma("unroll")                                                            \
          for (int r = 0; r < 16; r++) {                                               \
            const int rowl = wm * 64 + mi * 32 + (r & 3) + ((r >> 2) << 3) + (lhi << 2);\
            float v = acc[mi][ni][r] + bias;                                           \
            v = (gg == 2) ? tanhf(v) : (1.f / (1.f + __expf(-v)));                     \
            scr[rowl * 192 + pcol] = f2bf(v);                                          \
          }                                                                            \
        }                                                                              \
      }                                                                                \
      __syncthreads();                                                                 \
      u16* hout = ringS + (size_t)(t & 1) * RING_SLOT_E;                               \
      _Pragma("unroll")                                                                \
      for (int jj = 0; jj < 24; jj++) {                                                \
        const int idx = jj * 256 + tid;                                                \
        const int row = idx / 48;                                                      \
        const int hc  = idx - row * 48;                                                \
        const float iv = bf2f(scr[row * 192       + hc]);                              \
        const float fv = bf2f(scr[row * 192 +  48 + hc]);                              \
        const float gv = bf2f(scr[row * 192 +  96 + hc]);                              \
        const float ov = bf2f(scr[row * 192 + 144 + hc]);                              \
        const float cn = fv * c_reg[jj] + iv * gv;                                     \
        c_reg[jj] = cn;                                                                \
        const int colg = ntile * 48 + hc;                                              \
        hout[(size_t)(colg >> 5) * 16384 + (size_t)(mrow0 + row) * 32 + (colg & 31)]   \
            = f2bf(ov * tanhf(cn));                                                    \
      }                                                                                \
    }                                                                                  \
    __syncthreads();  /* drains h-stores (HIP emits vmcnt(0) before s_barrier) */      \
    if (tid == 0)                                                                      \
      __hip_atomic_fetch_add(Fself, 1u, __ATOMIC_RELEASE, __HIP_MEMORY_SCOPE_AGENT);   \
  }

// deep variant: 6 dynamic-LDS stages, 5 chunks in flight
__global__ __launch_bounds__(256, 1) void k_lstm_deep(
    const u16* __restrict__ xT,
    u16* __restrict__ ring0, u16* __restrict__ ring1, u16* __restrict__ ring2,
    const u16* __restrict__ W0, const u16* __restrict__ W1, const u16* __restrict__ W2,
    const float* __restrict__ pb, u32* __restrict__ flg) {
  LSTM_BODY(extern __shared__ __align__(16) unsigned char smem[], smem, NSTAGE, 1)
}

// static fallback: 3 stages, depth 2 (same dataflow sync + coherence)
__global__ __launch_bounds__(256, 2) void k_lstm(
    const u16* __restrict__ xT,
    u16* __restrict__ ring0, u16* __restrict__ ring1, u16* __restrict__ ring2,
    const u16* __restrict__ W0, const u16* __restrict__ W1, const u16* __restrict__ W2,
    const float* __restrict__ pb, u32* __restrict__ flg) {
  LSTM_BODY(__shared__ __align__(16) unsigned char smem[61440 + 768], smem, 3, 0)
}

// ---------------------------------------------------------------- projection + L2 norm
__global__ __launch_bounds__(256) void k_proj(const u16* __restrict__ hlast,
                                              const float* __restrict__ pw,
                                              const float* __restrict__ pbv,
                                              float* __restrict__ out) {
  __shared__ float hs[8 * 768];
  __shared__ float wred[4 * 8];
  __shared__ float inv[8];
  const int tid = threadIdx.x;
  const int r0 = blockIdx.x * 8;
  for (int i = tid; i < 8 * 768; i += 256) {
    const int b = i / 768, col = i - b * 768;   // chunked ring read
    hs[i] = bf2f(hlast[(size_t)(col >> 5) * 16384 + (size_t)(r0 + b) * 32 + (col & 31)]);
  }
  __syncthreads();
  float acc[8];
#pragma unroll
  for (int r = 0; r < 8; r++) acc[r] = 0.f;
  const float* wrow = pw + (size_t)tid * 768;
  for (int k = 0; k < 768; k++) {
    float w = wrow[k];
#pragma unroll
    for (int r = 0; r < 8; r++) acc[r] += hs[r * 768 + k] * w;
  }
  const float bv = pbv[tid];
#pragma unroll
  for (int r = 0; r < 8; r++) acc[r] += bv;
  const int lane = tid & 63, w4 = tid >> 6;
#pragma unroll
  for (int r = 0; r < 8; r++) {
    float v = acc[r] * acc[r];
#pragma unroll
    for (int off = 32; off > 0; off >>= 1) v += __shfl_xor(v, off);
    if (lane == 0) wred[w4 * 8 + r] = v;
  }
  __syncthreads();
  if (tid < 8) {
    float sum = wred[tid] + wred[8 + tid] + wred[16 + tid] + wred[24 + tid];
    inv[tid] = 1.f / sqrtf(sum);
  }
  __syncthreads();
#pragma unroll
  for (int r = 0; r < 8; r++) out[(size_t)(r0 + r) * 256 + tid] = acc[r] * inv[r];
}

// ---------------------------------------------------------------- host
extern "C" void kernel_launch(void* const* d_in, const int* in_sizes, int n_in,
                              void* d_out, int out_size, void* d_ws, size_t ws_size,
                              hipStream_t stream) {
  const float* x    = (const float*)d_in[0];
  const float* wih0 = (const float*)d_in[1];
  const float* whh0 = (const float*)d_in[2];
  const float* bi0  = (const float*)d_in[3];
  const float* bh0  = (const float*)d_in[4];
  const float* wih1 = (const float*)d_in[5];
  const float* whh1 = (const float*)d_in[6];
  const float* bi1  = (const float*)d_in[7];
  const float* bh1  = (const float*)d_in[8];
  const float* wih2 = (const float*)d_in[9];
  const float* whh2 = (const float*)d_in[10];
  const float* bi2  = (const float*)d_in[11];
  const float* bh2  = (const float*)d_in[12];
  const float* pw   = (const float*)d_in[13];
  const float* pbv  = (const float*)d_in[14];

  if (ws_size < WS_NEED) return;   // clean wrong answer, no OOB

  // host-side feasibility check for the deep (dynamic-LDS) variant — pure queries,
  // no stream ops, so graph capture cannot be poisoned. Fallback = static 3-stage.
  static int use_deep = -1;
  if (use_deep < 0) {
    hipError_t e1 = hipFuncSetAttribute((const void*)k_lstm_deep,
                                        hipFuncAttributeMaxDynamicSharedMemorySize,
                                        (int)DYN_LDS);
    int nb = 0;
    hipError_t e2 = hipOccupancyMaxActiveBlocksPerMultiprocessor(
        &nb, k_lstm_deep, 256, (size_t)DYN_LDS);
    use_deep = (e1 == hipSuccess && e2 == hipSuccess && nb >= 1) ? 1 : 0;
  }

  char* ws  = (char*)d_ws;
  u32*  flg = (u32*)(ws + 0);
  u16*  r0  = (u16*)(ws + OFF_R0);
  u16*  r1  = (u16*)(ws + OFF_R1);
  u16*  r2  = (u16*)(ws + OFF_R2);
  float* pb = (float*)(ws + OFF_PB);
  u16*  xT  = (u16*)(ws + OFF_XT);
  u16*  W0  = (u16*)(ws + OFF_W0);
  u16*  W1  = (u16*)(ws + OFF_W1);
  u16*  W2  = (u16*)(ws + OFF_W2);

  hipLaunchKernelGGL(k_zero, dim3(512), dim3(256), 0, stream,
                     (uint4*)ws, (int)(OFF_PB / 16));
  hipLaunchKernelGGL(k_pack_w, dim3((L0N + 2 * L12N + 255) / 256), dim3(256), 0, stream,
                     wih0, whh0, wih1, whh1, wih2, whh2, W0, W1, W2);
  hipLaunchKernelGGL(k_pack_b, dim3(36), dim3(256), 0, stream,
                     bi0, bh0, bi1, bh1, bi2, bh2, pb);
  hipLaunchKernelGGL(k_xT, dim3(kT * kB * 64 / 256), dim3(256), 0, stream, x, xT);

  {
    const u16* xTc = xT; const float* pbc = pb;
    const u16 *W0c = W0, *W1c = W1, *W2c = W2;
    u16 *r0m = r0, *r1m = r1, *r2m = r2; u32* flgm = flg;
    void* kargs[] = {(void*)&xTc, (void*)&r0m, (void*)&r1m, (void*)&r2m,
                     (void*)&W0c, (void*)&W1c, (void*)&W2c, (void*)&pbc, (void*)&flgm};
    if (use_deep) {
      hipLaunchCooperativeKernel((void*)k_lstm_deep, dim3(NBLK), dim3(256), kargs,
                                 (unsigned int)DYN_LDS, stream);
    } else {
      hipLaunchCooperativeKernel((void*)k_lstm, dim3(NBLK), dim3(256), kargs, 0, stream);
    }
  }

  hipLaunchKernelGGL(k_proj, dim3(64), dim3(256), 0, stream,
                     r2 + (size_t)((kT - 1) & 1) * RING_SLOT_E, pw, pbv, (float*)d_out);
}

// Round 9
// 8985.681 us; speedup vs baseline: 1.1106x; 1.0058x over previous
//
#include <hip/hip_runtime.h>
#include <cstdint>
#include <cstddef>

using u16 = unsigned short;
using u32 = unsigned int;

typedef __attribute__((ext_vector_type(8)))  __bf16 bf16x8;
typedef __attribute__((ext_vector_type(16))) float  f32x16;

constexpr int kB   = 512;
constexpr int kT   = 180;
constexpr int kH   = 768;
constexpr int NBLK3 = 384;  // 3 layers * 16 ntiles * 8 m-tiles (64 rows each)
constexpr int NBLK2 = 192;  // fallback geometry: 3 * 16 * 4 (128 rows)

constexpr int L0N  = 16 * 192 * 832;    // packed weights [ntile16][pcol192][K]
constexpr int L12N = 16 * 192 * 1536;

// h-ring: chunked layout [2 slots][24 kchunks][512 rows][32 k] bf16
constexpr int RING_SLOT_E = 24 * 512 * 32;               // 393,216 elems per slot
constexpr size_t RING_SZ  = (size_t)2 * RING_SLOT_E * 2; // 1,572,864 B

// workspace (bytes). Flags: 24 x 256B lines (3 layers x 8 mt) at ws+0 (zeroed).
constexpr size_t OFF_R0  = 16384;
constexpr size_t OFF_R1  = OFF_R0 + RING_SZ;
constexpr size_t OFF_R2  = OFF_R1 + RING_SZ;
constexpr size_t OFF_PB  = OFF_R2 + RING_SZ;             // zeroed region end
constexpr size_t OFF_XT  = OFF_PB + (size_t)3 * 3072 * 4;
constexpr size_t OFF_W0  = OFF_XT + (size_t)kT * kB * 64 * 2;
constexpr size_t OFF_W1  = OFF_W0 + (size_t)L0N * 2;
constexpr size_t OFF_W2  = OFF_W1 + (size_t)L12N * 2;
constexpr size_t WS_NEED = OFF_W2 + (size_t)L12N * 2;    // ~40.5 MB

#define CLB __asm__ volatile("" ::: "memory")

__device__ __forceinline__ float bf2f(u16 u) {
  union { u32 i; float f; } v; v.i = ((u32)u) << 16; return v.f;
}
__device__ __forceinline__ u16 f2bf(float f) {
  union { float f; u32 i; } v; v.f = f;
  u32 r = v.i + 0x7fffu + ((v.i >> 16) & 1u);
  return (u16)(r >> 16);
}

// async global->LDS, 16B per lane (wave-uniform LDS base + lane*16; dests lane-linear)
// All reads cached (aux=0); cross-XCD h coherence = producer RELEASE-add (wbl2) +
// consumer __threadfence() acquire after flag spins (R0/R8-proven scheme).
typedef __attribute__((address_space(1))) const u32 as1_u32;
typedef __attribute__((address_space(3))) u32 as3_u32;
__device__ __forceinline__ void gload_lds16(const u16* g, u16* l) {
  __builtin_amdgcn_global_load_lds((as1_u32*)g, (as3_u32*)l, 16, 0, 0);
}

// ---------------------------------------------------------------- zero
__global__ void k_zero(uint4* p, int n) {
  uint4 z = make_uint4(0u, 0u, 0u, 0u);
  for (int i = blockIdx.x * 256 + threadIdx.x; i < n; i += gridDim.x * 256) p[i] = z;
}

// ---------------------------------------------------------------- weight pack
// [ntile(16)][pcol(192)][K] bf16, K-contiguous per column.
// pcol = gate*48 + hc (i,f,g,o); global gate col = gate*768 + ntile*48 + hc.
// L0 K=832: k<40 w_ih0 | 40..63 zero | 64..831 w_hh0. L1/2 K=1536: k<768 ih else hh.
__global__ void k_pack_w(const float* __restrict__ wih0, const float* __restrict__ whh0,
                         const float* __restrict__ wih1, const float* __restrict__ whh1,
                         const float* __restrict__ wih2, const float* __restrict__ whh2,
                         u16* __restrict__ W0, u16* __restrict__ W1, u16* __restrict__ W2) {
  int idx = blockIdx.x * 256 + threadIdx.x;
  if (idx < L0N) {
    int col = idx / 832, k = idx - col * 832;
    int ntile = col / 192, p = col - ntile * 192;
    int g = p / 48, hc = p - g * 48;
    int gcol = g * 768 + ntile * 48 + hc;
    float v = (k < 40) ? wih0[gcol * 40 + k]
                       : ((k < 64) ? 0.f : whh0[(size_t)gcol * 768 + (k - 64)]);
    W0[idx] = f2bf(v);
  } else if (idx < L0N + L12N) {
    int li = idx - L0N;
    int col = li / 1536, k = li - col * 1536;
    int ntile = col / 192, p = col - ntile * 192;
    int g = p / 48, hc = p - g * 48;
    int gcol = g * 768 + ntile * 48 + hc;
    float v = (k < 768) ? wih1[(size_t)gcol * 768 + k] : whh1[(size_t)gcol * 768 + (k - 768)];
    W1[li] = f2bf(v);
  } else {
    int li = idx - (L0N + L12N);
    if (li < L12N) {
      int col = li / 1536, k = li - col * 1536;
      int ntile = col / 192, p = col - ntile * 192;
      int g = p / 48, hc = p - g * 48;
      int gcol = g * 768 + ntile * 48 + hc;
      float v = (k < 768) ? wih2[(size_t)gcol * 768 + k] : whh2[(size_t)gcol * 768 + (k - 768)];
      W2[li] = f2bf(v);
    }
  }
}

// ---------------------------------------------------------------- bias pack
__global__ void k_pack_b(const float* __restrict__ bi0, const float* __restrict__ bh0,
                         const float* __restrict__ bi1, const float* __restrict__ bh1,
                         const float* __restrict__ bi2, const float* __restrict__ bh2,
                         float* __restrict__ pbo) {
  int idx = blockIdx.x * 256 + threadIdx.x;   // 3*3072
  int l = idx / 3072, r = idx - l * 3072;
  int ntile = r / 192, p = r - ntile * 192;
  int g = p / 48, hc = p - g * 48;
  int gcol = g * 768 + ntile * 48 + hc;
  const float* bi = (l == 0) ? bi0 : ((l == 1) ? bi1 : bi2);
  const float* bh = (l == 0) ? bh0 : ((l == 1) ? bh1 : bh2);
  pbo[idx] = bi[gcol] + bh[gcol];
}

// ---------------------------------------------------------------- x transform
__global__ void k_xT(const float* __restrict__ x, u16* __restrict__ xT) {
  int idx = blockIdx.x * 256 + threadIdx.x;    // 180*512*64
  int t = idx / (512 * 64);
  int r = idx - t * 512 * 64;
  int b = r >> 6, j = r & 63;
  float v = (j < 40) ? x[((size_t)b * 180 + t) * 40 + j] : 0.f;
  xT[(size_t)t * 32768 + (size_t)(j >> 5) * 16384 + b * 32 + (j & 31)] = f2bf(v);
}

// ---------------------------------------------------------------- 384-block LSTM (3 blocks/CU)
// Theory: all prior variants ran 1 block/CU; the ~20 GB/s/CU staging invariant across
// depth/path/sync changes is CU idle time in waitcnt/barrier with no co-resident block
// to fill it (m97 GEMM: 55 GB/s/CU at ~3 blocks/CU). This kernel: 64-row m-tiles ->
// 384 blocks, 48KB static LDS + <=168 VGPR -> 3 blocks/CU; co-resident blocks overlap
// each other's stalls.
// Geometry: bid -> xcd=bid&7, j0=bid>>3; g=( j0>>3)*8+xcd; layer=g>>4, ntile=g&15,
// mt=j0&7, rows [mt*64,+64), cols [ntile*192,+192). XCD swizzle keeps the 8 m-twins
// of a weight slice on one XCD (weights L2-resident; B-traffic stays local-L2).
// Flags F[layer][mt] (24 x 256B lines, 16 ntile-producers each):
//   input ready (l>=1):  F[l-1][mt] >= 16(t+1)
//   recurrence  (t>=1):  F[l][mt]   >= 16t
//   WAR backpressure (l<=1, t>=2): F[l+1][mt] >= 16(t-1)
// Coherence: consumer __threadfence() after spins; producer RELEASE-add. (R8-proven.)
// K-loop: proven glds/vmcnt skeleton; 4 glds/thread/chunk (1 A + 3 B), 3 stages of
// 16KB (A[64][32k] 4KB @0, B[192][32k] 12KB @+4KB), depth-2: steady vmcnt(4), tail 0.
__global__ __launch_bounds__(256, 3) void k_lstm384(
    const u16* __restrict__ xT,
    u16* __restrict__ ring0, u16* __restrict__ ring1, u16* __restrict__ ring2,
    const u16* __restrict__ W0, const u16* __restrict__ W1, const u16* __restrict__ W2,
    const float* __restrict__ pb, u32* __restrict__ flg) {
  __shared__ __align__(16) unsigned char smem[49152];
  u16* scr = (u16*)smem;                 // epilogue scratch [64][192] (aliases stages)

  const int tid = threadIdx.x;
  const int bid = blockIdx.x;
  const int xcd = bid & 7, j0 = bid >> 3;          // j0 0..47
  const int g_    = (j0 >> 3) * 8 + xcd;           // 0..47
  const int mt    = j0 & 7;                        // 0..7
  const int layer = g_ >> 4;
  const int ntile = g_ & 15;
  const int mrow0 = mt * 64;

  const u16* Wl     = (layer == 0) ? W0 : ((layer == 1) ? W1 : W2);
  const int  Kl     = (layer == 0) ? 832 : 1536;
  const int  KcIn   = (layer == 0) ? 2 : 24;       // input k-chunks
  const int  nch    = (layer == 0) ? 26 : 48;
  const u16* inseq  = (layer == 1) ? ring0 : ring1;
  u16*       ringS  = (layer == 0) ? ring0 : ((layer == 1) ? ring1 : ring2);
  const u16* bbase0 = Wl + (size_t)(ntile * 192) * Kl;

  u32* Fself = flg + (size_t)(((layer << 3) | mt) * 64);
  u32* Fin   = flg + (size_t)((((layer - 1) << 3) | mt) * 64);  // valid if layer>=1
  u32* Fnxt  = flg + (size_t)((((layer + 1) << 3) | mt) * 64);  // valid if layer<=1

  const int wid = tid >> 6, lane = tid & 63;
  const int wm = wid & 1, wn = wid >> 1;           // 2 m-halves x 2 n-halves
  const int l31 = lane & 31, lhi = lane >> 5;

  // bias in registers: pcol = wn*96 + ni*32 + l31
  float bias_r[3];
#pragma unroll
  for (int ni = 0; ni < 3; ni++)
    bias_r[ni] = pb[layer * 3072 + ntile * 192 + wn * 96 + ni * 32 + l31];

  float c_reg[12];
#pragma unroll
  for (int i = 0; i < 12; i++) c_reg[i] = 0.f;

  for (int t = 0; t < kT; ++t) {
    if (tid == 0) {
      auto spinf = [&](u32* f, u32 goal) {
        u32 tries = 0;
        while (__hip_atomic_load(f, __ATOMIC_RELAXED, __HIP_MEMORY_SCOPE_AGENT) < goal) {
          __builtin_amdgcn_s_sleep(4);
          if (++tries > 400000u) break;
        }
      };
      if (layer >= 1)           spinf(Fin,   16u * (u32)(t + 1));
      if (t >= 1)               spinf(Fself, 16u * (u32)t);
      if (layer <= 1 && t >= 2) spinf(Fnxt,  16u * (u32)(t - 1));
      __threadfence();  // acquire: fresh cross-XCD h (R0/R8-proven)
    }
    __syncthreads();

    f32x16 acc[3];
#pragma unroll
    for (int ni = 0; ni < 3; ni++)
#pragma unroll
      for (int r = 0; r < 16; r++) acc[ni][r] = 0.f;

    const u16* inbase  = (layer == 0) ? (xT + (size_t)t * 32768)
                                      : (inseq + (size_t)(t & 1) * RING_SLOT_E);
    const u16* recbase = ringS + (size_t)((t - 1) & 1) * RING_SLOT_E; // t=0 -> slot1 zeros

    // stage chunk c into stage st: A 1 glds/thread + B 3 glds/thread (4/chunk)
    auto stage = [&](int c, int st) {
      u16* sbA = (u16*)(smem + (size_t)st * 16384);
      u16* sbB = sbA + 2048;               // +4096 bytes
      const u16* abase = (c < KcIn) ? (inbase + (size_t)c * 16384)
                                    : (recbase + (size_t)(c - KcIn) * 16384);
      {
        const int e = tid;                 // 0..255 = 64 rows x 4 slots
        const int row = e >> 2, sp = e & 3;
        const int so = sp ^ ((row >> 1) & 3);
        gload_lds16(abase + (size_t)(mrow0 + row) * 32 + so * 8, sbA + (size_t)e * 8);
      }
      const u16* bb = bbase0 + c * 32;
#pragma unroll
      for (int k = 0; k < 3; k++) {
        const int e = tid + k * 256;       // 0..767 = 192 cols x 4 slots
        const int col = e >> 2, sp = e & 3;
        const int so = sp ^ ((col >> 1) & 3);
        gload_lds16(bb + (size_t)col * Kl + so * 8, sbB + (size_t)e * 8);
      }
    };

    stage(0, 0);
    stage(1, 1);
    for (int c = 0; c < nch; ++c) {
      CLB;
      // 4 glds/thread/chunk, in-order: steady vmcnt(4) = chunk c landed; last vmcnt(0)
      if (c == nch - 1) __builtin_amdgcn_s_waitcnt(0x0F70);  // vmcnt(0)
      else              __builtin_amdgcn_s_waitcnt(0x0F74);  // vmcnt(4)
      __builtin_amdgcn_s_barrier();
      CLB;
      if (c + 2 < nch) stage(c + 2, (c + 2) % 3);
      const u16* sA = (const u16*)(smem + (size_t)(c % 3) * 16384);
      const u16* sB = sA + 2048;
      const int wsw = (l31 >> 1) & 3;
#pragma unroll
      for (int kk = 0; kk < 2; kk++) {
        const int sl = (((kk << 1) | lhi) ^ wsw) << 3;   // swizzled 16B slot
        bf16x8 a0 = *(const bf16x8*)(sA + (wm * 32 + l31) * 32 + sl);
        const int c0 = wn * 96 + l31;
        bf16x8 b0 = *(const bf16x8*)(sB + (c0     ) * 32 + sl);
        bf16x8 b1 = *(const bf16x8*)(sB + (c0 + 32) * 32 + sl);
        bf16x8 b2 = *(const bf16x8*)(sB + (c0 + 64) * 32 + sl);
        acc[0] = __builtin_amdgcn_mfma_f32_32x32x16_bf16(a0, b0, acc[0], 0, 0, 0);
        acc[1] = __builtin_amdgcn_mfma_f32_32x32x16_bf16(a0, b1, acc[1], 0, 0, 0);
        acc[2] = __builtin_amdgcn_mfma_f32_32x32x16_bf16(a0, b2, acc[2], 0, 0, 0);
      }
    }
    __syncthreads();   // all glds retired (vmcnt(0) on last iter); stages -> scr safe
    // epilogue: bias + nonlinearity (C/D: col=lane&31, row=(r&3)+8*(r>>2)+4*lhi)
#pragma unroll
    for (int ni = 0; ni < 3; ni++) {
      const int pcol = wn * 96 + ni * 32 + l31;
      const int gate = pcol / 48;
      const float bias = bias_r[ni];
#pragma unroll
      for (int r = 0; r < 16; r++) {
        const int rowl = wm * 32 + (r & 3) + ((r >> 2) << 3) + (lhi << 2);
        float v = acc[ni][r] + bias;
        v = (gate == 2) ? tanhf(v) : (1.f / (1.f + __expf(-v)));
        scr[rowl * 192 + pcol] = f2bf(v);
      }
    }
    __syncthreads();
    // pointwise: 3072 = 64 rows x 48 h-cols; c-state in registers
    u16* hout = ringS + (size_t)(t & 1) * RING_SLOT_E;
#pragma unroll
    for (int jj = 0; jj < 12; jj++) {
      const int idx = jj * 256 + tid;
      const int row = idx / 48;
      const int hc  = idx - row * 48;
      const float iv = bf2f(scr[row * 192       + hc]);
      const float fv = bf2f(scr[row * 192 +  48 + hc]);
      const float gv = bf2f(scr[row * 192 +  96 + hc]);
      const float ov = bf2f(scr[row * 192 + 144 + hc]);
      const float cn = fv * c_reg[jj] + iv * gv;
      c_reg[jj] = cn;
      const int colg = ntile * 48 + hc;
      hout[(size_t)(colg >> 5) * 16384 + (size_t)(mrow0 + row) * 32 + (colg & 31)]
          = f2bf(ov * tanhf(cn));
    }
    __syncthreads();  // drains h-stores (HIP emits vmcnt(0) before s_barrier)
    if (tid == 0)
      __hip_atomic_fetch_add(Fself, 1u, __ATOMIC_RELEASE, __HIP_MEMORY_SCOPE_AGENT);
  }
}

// ---------------------------------------------------------------- fallback (192-block,
// R8-static geometry: 128-row tiles, 62KB LDS, depth-2, flags+fence). Same proven frame.
__global__ __launch_bounds__(256, 2) void k_lstm192(
    const u16* __restrict__ xT,
    u16* __restrict__ ring0, u16* __restrict__ ring1, u16* __restrict__ ring2,
    const u16* __restrict__ W0, const u16* __restrict__ W1, const u16* __restrict__ W2,
    const float* __restrict__ pb, u32* __restrict__ flg) {
  __shared__ __align__(16) unsigned char smem[61440 + 768];
  u16*   scr = (u16*)smem;
  float* pbs = (float*)(smem + 61440);

  const int tid = threadIdx.x;
  const int bid = blockIdx.x;
  const int xcd = bid & 7, j0 = bid >> 3;
  const int g_    = (j0 >> 2) * 8 + xcd;
  const int mt    = j0 & 3;
  const int layer = g_ >> 4;
  const int ntile = g_ & 15;
  const int mrow0 = mt * 128;

  const u16* Wl     = (layer == 0) ? W0 : ((layer == 1) ? W1 : W2);
  const int  Kl     = (layer == 0) ? 832 : 1536;
  const int  KcIn   = (layer == 0) ? 2 : 24;
  const int  nch    = (layer == 0) ? 26 : 48;
  const u16* inseq  = (layer == 1) ? ring0 : ring1;
  u16*       ringS  = (layer == 0) ? ring0 : ((layer == 1) ? ring1 : ring2);
  const u16* bbase0 = Wl + (size_t)(ntile * 192) * Kl;

  u32* Fself = flg + (size_t)(((layer << 3) | (mt << 1)) * 64);   // reuse 8-slot stride
  u32* Fin   = flg + (size_t)((((layer - 1) << 3) | (mt << 1)) * 64);
  u32* Fnxt  = flg + (size_t)((((layer + 1) << 3) | (mt << 1)) * 64);

  for (int i = tid; i < 192; i += 256) pbs[i] = pb[layer * 3072 + ntile * 192 + i];

  const int wid = tid >> 6, lane = tid & 63;
  const int wm = wid & 1, wn = wid >> 1;
  const int l31 = lane & 31, lhi = lane >> 5;

  float c_reg[24];
#pragma unroll
  for (int i = 0; i < 24; i++) c_reg[i] = 0.f;

  for (int t = 0; t < kT; ++t) {
    if (tid == 0) {
      auto spinf = [&](u32* f, u32 goal) {
        u32 tries = 0;
        while (__hip_atomic_load(f, __ATOMIC_RELAXED, __HIP_MEMORY_SCOPE_AGENT) < goal) {
          __builtin_amdgcn_s_sleep(4);
          if (++tries > 400000u) break;
        }
      };
      if (layer >= 1)           spinf(Fin,   16u * (u32)(t + 1));
      if (t >= 1)               spinf(Fself, 16u * (u32)t);
      if (layer <= 1 && t >= 2) spinf(Fnxt,  16u * (u32)(t - 1));
      __threadfence();
    }
    __syncthreads();

    f32x16 acc[2][3];
#pragma unroll
    for (int mi = 0; mi < 2; mi++)
#pragma unroll
      for (int ni = 0; ni < 3; ni++)
#pragma unroll
        for (int r = 0; r < 16; r++) acc[mi][ni][r] = 0.f;

    const u16* inbase  = (layer == 0) ? (xT + (size_t)t * 32768)
                                      : (inseq + (size_t)(t & 1) * RING_SLOT_E);
    const u16* recbase = ringS + (size_t)((t - 1) & 1) * RING_SLOT_E;

    auto stage = [&](int c, int st) {
      u16* sbA = (u16*)(smem + st * 20480);
      u16* sbB = sbA + 4096;
      const u16* abase = (c < KcIn) ? (inbase + (size_t)c * 16384)
                                    : (recbase + (size_t)(c - KcIn) * 16384);
#pragma unroll
      for (int k = 0; k < 2; k++) {
        const int e = tid + k * 256;
        const int row = e >> 2, sp = e & 3;
        const int so = sp ^ ((row >> 1) & 3);
        gload_lds16(abase + (size_t)(mrow0 + row) * 32 + so * 8, sbA + (size_t)e * 8);
      }
      const u16* bb = bbase0 + c * 32;
#pragma unroll
      for (int k = 0; k < 3; k++) {
        const int e = tid + k * 256;
        const int col = e >> 2, sp = e & 3;
        const int so = sp ^ ((col >> 1) & 3);
        gload_lds16(bb + (size_t)col * Kl + so * 8, sbB + (size_t)e * 8);
      }
    };

    stage(0, 0);
    stage(1, 1);
    for (int c = 0; c < nch; ++c) {
      CLB;
      if (c == nch - 1) __builtin_amdgcn_s_waitcnt(0x0F70);  // vmcnt(0)
      else              __builtin_amdgcn_s_waitcnt(0x0F75);  // vmcnt(5)
      __builtin_amdgcn_s_barrier();
      CLB;
      if (c + 2 < nch) stage(c + 2, (c + 2) % 3);
      const u16* sA = (const u16*)(smem + (c % 3) * 20480);
      const u16* sB = sA + 4096;
      const int wsw = (l31 >> 1) & 3;
#pragma unroll
      for (int kk = 0; kk < 2; kk++) {
        const int sl = (((kk << 1) | lhi) ^ wsw) << 3;
        bf16x8 a0 = *(const bf16x8*)(sA + (wm * 64 +      l31) * 32 + sl);
        bf16x8 a1 = *(const bf16x8*)(sA + (wm * 64 + 32 + l31) * 32 + sl);
        const int c0 = wn * 96 + l31;
        bf16x8 b0 = *(const bf16x8*)(sB + (c0     ) * 32 + sl);
        bf16x8 b1 = *(const bf16x8*)(sB + (c0 + 32) * 32 + sl);
        bf16x8 b2 = *(const bf16x8*)(sB + (c0 + 64) * 32 + sl);
        acc[0][0] = __builtin_amdgcn_mfma_f32_32x32x16_bf16(a0, b0, acc[0][0], 0, 0, 0);
        acc[0][1] = __builtin_amdgcn_mfma_f32_32x32x16_bf16(a0, b1, acc[0][1], 0, 0, 0);
        acc[0][2] = __builtin_amdgcn_mfma_f32_32x32x16_bf16(a0, b2, acc[0][2], 0, 0, 0);
        acc[1][0] = __builtin_amdgcn_mfma_f32_32x32x16_bf16(a1, b0, acc[1][0], 0, 0, 0);
        acc[1][1] = __builtin_amdgcn_mfma_f32_32x32x16_bf16(a1, b1, acc[1][1], 0, 0, 0);
        acc[1][2] = __builtin_amdgcn_mfma_f32_32x32x16_bf16(a1, b2, acc[1][2], 0, 0, 0);
      }
    }
    __syncthreads();
#pragma unroll
    for (int mi = 0; mi < 2; mi++) {
#pragma unroll
      for (int ni = 0; ni < 3; ni++) {
        const int pcol = wn * 96 + ni * 32 + l31;
        const int gg = pcol / 48;
        const float bias = pbs[pcol];
#pragma unroll
        for (int r = 0; r < 16; r++) {
          const int rowl = wm * 64 + mi * 32 + (r & 3) + ((r >> 2) << 3) + (lhi << 2);
          float v = acc[mi][ni][r] + bias;
          v = (gg == 2) ? tanhf(v) : (1.f / (1.f + __expf(-v)));
          scr[rowl * 192 + pcol] = f2bf(v);
        }
      }
    }
    __syncthreads();
    u16* hout = ringS + (size_t)(t & 1) * RING_SLOT_E;
#pragma unroll
    for (int jj = 0; jj < 24; jj++) {
      const int idx = jj * 256 + tid;
      const int row = idx / 48;
      const int hc  = idx - row * 48;
      const float iv = bf2f(scr[row * 192       + hc]);
      const float fv = bf2f(scr[row * 192 +  48 + hc]);
      const float gv = bf2f(scr[row * 192 +  96 + hc]);
      const float ov = bf2f(scr[row * 192 + 144 + hc]);
      const float cn = fv * c_reg[jj] + iv * gv;
      c_reg[jj] = cn;
      const int colg = ntile * 48 + hc;
      hout[(size_t)(colg >> 5) * 16384 + (size_t)(mrow0 + row) * 32 + (colg & 31)]
          = f2bf(ov * tanhf(cn));
    }
    __syncthreads();
    if (tid == 0)
      __hip_atomic_fetch_add(Fself, 1u, __ATOMIC_RELEASE, __HIP_MEMORY_SCOPE_AGENT);
  }
}

// ---------------------------------------------------------------- projection + L2 norm
__global__ __launch_bounds__(256) void k_proj(const u16* __restrict__ hlast,
                                              const float* __restrict__ pw,
                                              const float* __restrict__ pbv,
                                              float* __restrict__ out) {
  __shared__ float hs[8 * 768];
  __shared__ float wred[4 * 8];
  __shared__ float inv[8];
  const int tid = threadIdx.x;
  const int r0 = blockIdx.x * 8;
  for (int i = tid; i < 8 * 768; i += 256) {
    const int b = i / 768, col = i - b * 768;   // chunked ring read
    hs[i] = bf2f(hlast[(size_t)(col >> 5) * 16384 + (size_t)(r0 + b) * 32 + (col & 31)]);
  }
  __syncthreads();
  float acc[8];
#pragma unroll
  for (int r = 0; r < 8; r++) acc[r] = 0.f;
  const float* wrow = pw + (size_t)tid * 768;
  for (int k = 0; k < 768; k++) {
    float w = wrow[k];
#pragma unroll
    for (int r = 0; r < 8; r++) acc[r] += hs[r * 768 + k] * w;
  }
  const float bv = pbv[tid];
#pragma unroll
  for (int r = 0; r < 8; r++) acc[r] += bv;
  const int lane = tid & 63, w4 = tid >> 6;
#pragma unroll
  for (int r = 0; r < 8; r++) {
    float v = acc[r] * acc[r];
#pragma unroll
    for (int off = 32; off > 0; off >>= 1) v += __shfl_xor(v, off);
    if (lane == 0) wred[w4 * 8 + r] = v;
  }
  __syncthreads();
  if (tid < 8) {
    float sum = wred[tid] + wred[8 + tid] + wred[16 + tid] + wred[24 + tid];
    inv[tid] = 1.f / sqrtf(sum);
  }
  __syncthreads();
#pragma unroll
  for (int r = 0; r < 8; r++) out[(size_t)(r0 + r) * 256 + tid] = acc[r] * inv[r];
}

// ---------------------------------------------------------------- host
extern "C" void kernel_launch(void* const* d_in, const int* in_sizes, int n_in,
                              void* d_out, int out_size, void* d_ws, size_t ws_size,
                              hipStream_t stream) {
  const float* x    = (const float*)d_in[0];
  const float* wih0 = (const float*)d_in[1];
  const float* whh0 = (const float*)d_in[2];
  const float* bi0  = (const float*)d_in[3];
  const float* bh0  = (const float*)d_in[4];
  const float* wih1 = (const float*)d_in[5];
  const float* whh1 = (const float*)d_in[6];
  const float* bi1  = (const float*)d_in[7];
  const float* bh1  = (const float*)d_in[8];
  const float* wih2 = (const float*)d_in[9];
  const float* whh2 = (const float*)d_in[10];
  const float* bi2  = (const float*)d_in[11];
  const float* bh2  = (const float*)d_in[12];
  const float* pw   = (const float*)d_in[13];
  const float* pbv  = (const float*)d_in[14];

  if (ws_size < WS_NEED) return;   // clean wrong answer, no OOB

  // host-side co-residency check for the 384-block variant (pure queries, capture-safe)
  static int mode = -1;   // 1 = 384-block, 0 = 192-block fallback
  if (mode < 0) {
    int nb = 0;
    hipError_t e1 = hipOccupancyMaxActiveBlocksPerMultiprocessor(&nb, k_lstm384, 256, 0);
    int dev = 0; hipGetDevice(&dev);
    hipDeviceProp_t props{};
    hipError_t e2 = hipGetDeviceProperties(&props, dev);
    mode = (e1 == hipSuccess && e2 == hipSuccess &&
            nb * props.multiProcessorCount >= NBLK3) ? 1 : 0;
  }

  char* ws  = (char*)d_ws;
  u32*  flg = (u32*)(ws + 0);
  u16*  r0  = (u16*)(ws + OFF_R0);
  u16*  r1  = (u16*)(ws + OFF_R1);
  u16*  r2  = (u16*)(ws + OFF_R2);
  float* pb = (float*)(ws + OFF_PB);
  u16*  xT  = (u16*)(ws + OFF_XT);
  u16*  W0  = (u16*)(ws + OFF_W0);
  u16*  W1  = (u16*)(ws + OFF_W1);
  u16*  W2  = (u16*)(ws + OFF_W2);

  hipLaunchKernelGGL(k_zero, dim3(512), dim3(256), 0, stream,
                     (uint4*)ws, (int)(OFF_PB / 16));
  hipLaunchKernelGGL(k_pack_w, dim3((L0N + 2 * L12N + 255) / 256), dim3(256), 0, stream,
                     wih0, whh0, wih1, whh1, wih2, whh2, W0, W1, W2);
  hipLaunchKernelGGL(k_pack_b, dim3(36), dim3(256), 0, stream,
                     bi0, bh0, bi1, bh1, bi2, bh2, pb);
  hipLaunchKernelGGL(k_xT, dim3(kT * kB * 64 / 256), dim3(256), 0, stream, x, xT);

  {
    const u16* xTc = xT; const float* pbc = pb;
    const u16 *W0c = W0, *W1c = W1, *W2c = W2;
    u16 *r0m = r0, *r1m = r1, *r2m = r2; u32* flgm = flg;
    void* kargs[] = {(void*)&xTc, (void*)&r0m, (void*)&r1m, (void*)&r2m,
                     (void*)&W0c, (void*)&W1c, (void*)&W2c, (void*)&pbc, (void*)&flgm};
    if (mode == 1) {
      hipError_t le = hipLaunchCooperativeKernel((void*)k_lstm384, dim3(NBLK3),
                                                 dim3(256), kargs, 0, stream);
      if (le != hipSuccess) mode = 0;
    }
    if (mode == 0) {
      hipLaunchCooperativeKernel((void*)k_lstm192, dim3(NBLK2), dim3(256),
                                 kargs, 0, stream);
    }
  }

  hipLaunchKernelGGL(k_proj, dim3(64), dim3(256), 0, stream,
                     r2 + (size_t)((kT - 1) & 1) * RING_SLOT_E, pw, pbv, (float*)d_out);
}